// Round 9
// baseline (1129.672 us; speedup 1.0000x reference)
//
#include <hip/hip_runtime.h>
#include <math.h>

#define NPTS 16384
#define PPB  2048
#define KNN  20

// ---------------- workspace layout (bytes), total 64 MiB ----------------
#define OFF_WT1H  0u
#define OFF_WT1L  8192u
#define OFF_WT2H  16384u
#define OFF_WT2L  49152u
#define OFF_WT3H  81920u
#define OFF_WT3L  212992u
#define OFF_N2    1048576u
#define OFF_IDX   1114112u     // 16384*20*4
#define OFF_POOL  2760704u     // 8192*4
#define OFF_C1    2793472u
#define OFF_C2    2809856u
#define OFF_X1    4194304u     // 16384*64*4  (dead after packA; reused by head partials)
#define OFF_P1    4194304u
#define OFF_P2    4325376u
#define OFF_X2    8388608u     // 16384*128*4
#define OFF_X3    16777216u    // 16384*256*4 (holds X bf16 planes until agg-3 writes x3)
#define OFF_XPH   16777216u
#define OFF_XPL   25165824u
#define OFF_UV    33554432u    // U|V per stage -> packed-A planes for fc1
#define OFF_APKH  33554432u
#define OFF_APKL  48234496u
#define OFF_BTH   0u
#define OFF_BTL   917504u

typedef __attribute__((ext_vector_type(8))) short b16x8;
typedef __attribute__((ext_vector_type(4))) float f32x4;

__device__ __forceinline__ unsigned f2o(float f) {
    unsigned u = __float_as_uint(f);
    return (u & 0x80000000u) ? ~u : (u | 0x80000000u);
}
__device__ __forceinline__ float o2f(unsigned u) {
    return (u & 0x80000000u) ? __uint_as_float(u & 0x7fffffffu) : __uint_as_float(~u);
}

// split fp32 -> (hi, lo) bf16 pair, RNE both; x ~= hi + lo to ~2^-18 rel
__device__ __forceinline__ void split_bf16(float x, unsigned short& h, unsigned short& l) {
    unsigned u = __float_as_uint(x);
    unsigned rh = (u + 0x7fffu + ((u >> 16) & 1u)) & 0xffff0000u;
    h = (unsigned short)(rh >> 16);
    float r = x - __uint_as_float(rh);
    unsigned v = __float_as_uint(r);
    l = (unsigned short)((v + 0x7fffu + ((v >> 16) & 1u)) >> 16);
}

// register top-20 insert: replace worst slot, rescan for new worst
__device__ __forceinline__ void topk_insert(float (&bd)[KNN], int (&bi)[KNN],
                                            float& worst, int& wslot, float v, int q) {
    #pragma unroll
    for (int s = 0; s < KNN; ++s) if (s == wslot) { bd[s] = v; bi[s] = q; }
    float w = bd[0]; int sl = 0;
    #pragma unroll
    for (int s = 1; s < KNN; ++s) if (bd[s] > w) { w = bd[s]; sl = s; }
    worst = w; wslot = sl;
}

// ---------------- prep kernels ----------------
__global__ void init_pool_kernel(unsigned* __restrict__ pool) {
    pool[blockIdx.x * 256 + threadIdx.x] = 0u;
}

template<int D>
__global__ void sqnorm_kernel(const float* __restrict__ X, float* __restrict__ n2) {
    int p = blockIdx.x * 256 + threadIdx.x;
    float s = 0.f;
    #pragma unroll
    for (int k = 0; k < D; k += 4) {
        float4 v = *(const float4*)&X[(size_t)p * D + k];
        s += v.x * v.x + v.y * v.y + v.z * v.z + v.w * v.w;
    }
    n2[p] = s;
}

// stage-1: pos [16384][3] -> bf16 hi/lo planes [16384][32] (cols 3..31 zero) + n2
__global__ void packX0_kernel(const float* __restrict__ pos,
                              unsigned short* __restrict__ Xh, unsigned short* __restrict__ Xl,
                              float* __restrict__ n2) {
    int p = blockIdx.x * 256 + threadIdx.x;
    float x = pos[p * 3 + 0], y = pos[p * 3 + 1], z = pos[p * 3 + 2];
    n2[p] = x * x + y * y + z * z;
    ushort4 h = {0, 0, 0, 0}, l = {0, 0, 0, 0};
    split_bf16(x, h.x, l.x); split_bf16(y, h.y, l.y); split_bf16(z, h.z, l.z);
    ushort4 zed = {0, 0, 0, 0};
    *(ushort4*)&Xh[(size_t)p * 32] = h;
    *(ushort4*)&Xl[(size_t)p * 32] = l;
    #pragma unroll
    for (int c = 4; c < 32; c += 4) {
        *(ushort4*)&Xh[(size_t)p * 32 + c] = zed;
        *(ushort4*)&Xl[(size_t)p * 32 + c] = zed;
    }
}

// pack X [16384 x K] fp32 -> bf16 hi/lo planes
__global__ void packX_kernel(const float* __restrict__ X,
                             unsigned short* __restrict__ Xh, unsigned short* __restrict__ Xl) {
    int e = blockIdx.x * 256 + threadIdx.x;
    float4 v = *(const float4*)&X[4 * (size_t)e];
    ushort4 h, l;
    split_bf16(v.x, h.x, l.x); split_bf16(v.y, h.y, l.y);
    split_bf16(v.z, h.z, l.z); split_bf16(v.w, h.w, l.w);
    *(ushort4*)&Xh[4 * (size_t)e] = h;
    *(ushort4*)&Xl[4 * (size_t)e] = l;
}

// W [2d][od] -> W^T hi/lo planes [2od][dpad]: n<od: U = W_top - W_bot; else V = W_bot
__global__ void packWt_kernel(const float* __restrict__ W,
                              unsigned short* __restrict__ Bh, unsigned short* __restrict__ Bl,
                              int d, int dpad, int od) {
    int e = blockIdx.x * 256 + threadIdx.x;
    int n = e / dpad, k = e - n * dpad;
    float v = 0.f;
    if (k < d) v = (n < od) ? (W[k * od + n] - W[(d + k) * od + n])
                            : W[(d + k) * od + (n - od)];
    unsigned short h, l;
    split_bf16(v, h, l);
    Bh[e] = h; Bl[e] = l;
}

// pack A = concat(x1,x2,x3) [16384 x 448] into bf16 hi/lo planes
__global__ void packA_kernel(const float* __restrict__ x1, const float* __restrict__ x2,
                             const float* __restrict__ x3,
                             unsigned short* __restrict__ Ah, unsigned short* __restrict__ Al) {
    int e = blockIdx.x * 256 + threadIdx.x;
    int m = e / 112, c4 = (e - m * 112) * 4;
    float4 v;
    if (c4 < 64)       v = *(const float4*)&x1[(size_t)m * 64 + c4];
    else if (c4 < 192) v = *(const float4*)&x2[(size_t)m * 128 + (c4 - 64)];
    else               v = *(const float4*)&x3[(size_t)m * 256 + (c4 - 192)];
    ushort4 h, l;
    split_bf16(v.x, h.x, l.x); split_bf16(v.y, h.y, l.y);
    split_bf16(v.z, h.z, l.z); split_bf16(v.w, h.w, l.w);
    *(ushort4*)&Ah[(size_t)m * 448 + c4] = h;
    *(ushort4*)&Al[(size_t)m * 448 + c4] = l;
}

// pack Wf1^T [1024 x 448] into bf16 hi/lo planes
__global__ void packB_kernel(const float* __restrict__ Wf1,
                             unsigned short* __restrict__ Bh, unsigned short* __restrict__ Bl) {
    int e = blockIdx.x * 256 + threadIdx.x;
    int n = e / 112, k4 = (e - n * 112) * 4;
    ushort4 h, l;
    float v0 = Wf1[(size_t)(k4 + 0) * 1024 + n];
    float v1 = Wf1[(size_t)(k4 + 1) * 1024 + n];
    float v2 = Wf1[(size_t)(k4 + 2) * 1024 + n];
    float v3 = Wf1[(size_t)(k4 + 3) * 1024 + n];
    split_bf16(v0, h.x, l.x); split_bf16(v1, h.y, l.y);
    split_bf16(v2, h.z, l.z); split_bf16(v3, h.w, l.w);
    *(ushort4*)&Bh[(size_t)n * 448 + k4] = h;
    *(ushort4*)&Bl[(size_t)n * 448 + k4] = l;
}

// ---------------- fused kNN v2: 16-row blocks, threshold-filtered select ----------------
// block: 16 rows x 2048 candidates, 16 chunks of 128. 4 waves: wave w owns cols
// [32w, 32w+32) (2 col-tiles) x 16 rows (1 row-tile). Select: 16 threads/row, each
// scans 8 cols/chunk; shared row-threshold tau (min of local 20th-bests) pre-filters;
// survivors buffered FIFO and drained via ballot loop (rare after warm-up).
template<int K>
__global__ __launch_bounds__(256, 4)
void knn_fused16_kernel(const unsigned short* __restrict__ Xh, const unsigned short* __restrict__ Xl,
                        const float* __restrict__ n2, int* __restrict__ idxout) {
    __shared__ unsigned short sA[2][16 * 40];      // 2560 B
    __shared__ unsigned short sB[2][128 * 40];     // 20480 B
    __shared__ float Ds[16 * 132];                 // 8448 B

    const int t = threadIdx.x;
    const int rb = blockIdx.x * 16;
    const int qbase = (rb >> 11) << 11;            // batch-local candidates
    const int w = t >> 6, l = t & 63;
    const int lm = l & 15, lq = l >> 4;
    const int r = t >> 4, sub = t & 15;            // select mapping: 16 threads/row

    float bd[KNN]; int bi[KNN];
    #pragma unroll
    for (int s = 0; s < KNN; ++s) { bd[s] = 3.0e38f; bi[s] = 0; }
    float worst = 3.0e38f; int wslot = 0;
    float tau = 3.3e38f;                           // shared row threshold (valid filter)
    float pv[8]; int pq[8];                        // FIFO pending buffer

    for (int qt = 0; qt < 16; ++qt) {
        const int qb = qbase + qt * 128;
        f32x4 acc[2];
        acc[0] = (f32x4){0.f, 0.f, 0.f, 0.f};
        acc[1] = (f32x4){0.f, 0.f, 0.f, 0.f};

        for (int kc = 0; kc < K; kc += 32) {
            __syncthreads();                        // sB/sA consumers done
            #pragma unroll
            for (int i = 0; i < 5; ++i) {           // 1152 16B chunks: A 128, B 1024
                int c = t + i * 256;
                if (c < 1152) {
                    const unsigned short* gsrc;
                    unsigned short* ldst;
                    if (c < 128) {
                        int plane = (c >> 6) & 1, rem = c & 63;
                        int m = rem >> 2, q = rem & 3;
                        gsrc = (plane ? Xl : Xh) + (size_t)(rb + m) * K + kc + q * 8;
                        ldst = &sA[plane][m * 40 + q * 8];
                    } else {
                        int c2 = c - 128;
                        int plane = c2 >> 9, idx = c2 & 511;
                        int m = idx >> 2, q = idx & 3;
                        gsrc = (plane ? Xl : Xh) + (size_t)(qb + m) * K + kc + q * 8;
                        ldst = &sB[plane][m * 40 + q * 8];
                    }
                    *(uint4*)ldst = *(const uint4*)gsrc;
                }
            }
            __syncthreads();
            b16x8 ah, al, bh[2], bl[2];
            {
                int off = lm * 40 + lq * 8;
                ah = *(const b16x8*)&sA[0][off];
                al = *(const b16x8*)&sA[1][off];
            }
            #pragma unroll
            for (int ct = 0; ct < 2; ++ct) {
                int off = (w * 32 + ct * 16 + lm) * 40 + lq * 8;
                bh[ct] = *(const b16x8*)&sB[0][off];
                bl[ct] = *(const b16x8*)&sB[1][off];
            }
            #pragma unroll
            for (int ct = 0; ct < 2; ++ct) {
                acc[ct] = __builtin_amdgcn_mfma_f32_16x16x32_bf16(ah, bh[ct], acc[ct], 0, 0, 0);
                acc[ct] = __builtin_amdgcn_mfma_f32_16x16x32_bf16(ah, bl[ct], acc[ct], 0, 0, 0);
                acc[ct] = __builtin_amdgcn_mfma_f32_16x16x32_bf16(al, bh[ct], acc[ct], 0, 0, 0);
            }
        }
        float nv[2];
        #pragma unroll
        for (int ct = 0; ct < 2; ++ct) nv[ct] = n2[qb + w * 32 + ct * 16 + lm];
        __syncthreads();                            // prev select done reading Ds
        // C-layout rows = lq*4+rr; writes quarter-wave conflict-free (lm spans banks)
        #pragma unroll
        for (int ct = 0; ct < 2; ++ct)
            #pragma unroll
            for (int rr = 0; rr < 4; ++rr)
                Ds[(lq * 4 + rr) * 132 + w * 32 + ct * 16 + lm] = nv[ct] - 2.f * acc[ct][rr];
        __syncthreads();
        // select: thread (r,sub) reads groups {sub, sub+16} (2-way LDS, free)
        int pcnt = 0;
        #pragma unroll
        for (int j = 0; j < 2; ++j) {
            float4 v = *(const float4*)&Ds[r * 132 + 4 * sub + 64 * j];
            int q0 = qt * 128 + 4 * sub + 64 * j;
            float vv[4] = {v.x, v.y, v.z, v.w};
            #pragma unroll
            for (int jj = 0; jj < 4; ++jj) {
                if (vv[jj] < tau) {                 // tau <= local worst always
                    #pragma unroll
                    for (int s = 0; s < 8; ++s) if (s == pcnt) { pv[s] = vv[jj]; pq[s] = q0 + jj; }
                    ++pcnt;
                }
            }
        }
        // drain FIFO (ballot loop; rare after ~3 chunks)
        int prd = 0;
        while (__ballot(prd < pcnt)) {
            if (prd < pcnt) {
                float x = 0.f; int q = 0;
                #pragma unroll
                for (int s = 0; s < 8; ++s) if (s == prd) { x = pv[s]; q = pq[s]; }
                if (x < worst) topk_insert(bd, bi, worst, wslot, x, q);
                ++prd;
            }
        }
        // tighten tau: min of local worsts over the 16-lane row group
        float tw = worst;
        #pragma unroll
        for (int m = 1; m < 16; m <<= 1) tw = fminf(tw, __shfl_xor(tw, m, 64));
        tau = tw;
    }

    // merge 16 lists of 20 -> top-20 per row: 20 rounds of 16-lane argmin butterfly
    __syncthreads();
    int* DsI = (int*)Ds;                            // row stride 132 ints
    float mv = 3.3e38f; int mq = 1 << 20, mj = 0;
    #pragma unroll
    for (int s = 0; s < KNN; ++s) {
        float x = bd[s]; int q = bi[s];
        if (x < mv || (x == mv && q < mq)) { mv = x; mq = q; mj = s; }
    }
    for (int round = 0; round < KNN; ++round) {
        float rv = mv; int rq = mq;
        #pragma unroll
        for (int m = 1; m < 16; m <<= 1) {
            float ov = __shfl_xor(rv, m, 64);
            int   oq = __shfl_xor(rq, m, 64);
            if (ov < rv || (ov == rv && oq < rq)) { rv = ov; rq = oq; }
        }
        if (sub == 0) DsI[r * 132 + round] = rq;
        if (mv == rv && mq == rq) {                 // I own the winner: consume + rescan
            #pragma unroll
            for (int s = 0; s < KNN; ++s) if (s == mj) bd[s] = 3.3e38f;
            mv = 3.3e38f; mq = 1 << 20; mj = 0;
            #pragma unroll
            for (int s = 0; s < KNN; ++s) {
                float x = bd[s]; int q = bi[s];
                if (x < mv || (x == mv && q < mq)) { mv = x; mq = q; mj = s; }
            }
        }
    }
    for (int s = sub; s < KNN; s += 16)
        idxout[(size_t)(rb + r) * KNN + s] = qbase + DsI[r * 132 + s];
}

// ---------------- UV projection: split-bf16 MFMA (all stages) ----------------
template<int K>
__global__ __launch_bounds__(256)
void gemm_uv_mfma(const unsigned short* __restrict__ Ah, const unsigned short* __restrict__ Al,
                  const unsigned short* __restrict__ Bh, const unsigned short* __restrict__ Bl,
                  float* __restrict__ C, int N) {
    __shared__ __align__(16) unsigned char smem[40960];
    unsigned short (*sA)[5120] = (unsigned short (*)[5120])smem;
    unsigned short (*sB)[5120] = (unsigned short (*)[5120])(smem + 20480);
    float* tile = (float*)smem;

    const int t = threadIdx.x;
    const int rb = blockIdx.x * 128, nb = blockIdx.y * 128;
    const int w = t >> 6, l = t & 63;
    const int wm = w & 1, wn = w >> 1;
    const int lm = l & 15, lq = l >> 4;

    f32x4 acc[4][4];
    #pragma unroll
    for (int i = 0; i < 4; ++i)
        #pragma unroll
        for (int j = 0; j < 4; ++j) acc[i][j] = (f32x4){0.f, 0.f, 0.f, 0.f};

    for (int kc = 0; kc < K; kc += 32) {
        __syncthreads();
        #pragma unroll
        for (int i = 0; i < 8; ++i) {
            int c = t + i * 256;
            int idx = c & 511, m = idx >> 2, q = idx & 3;
            int plane = (c >> 9) & 1;
            const unsigned short* gsrc;
            unsigned short* ldst;
            if (c < 1024) {
                gsrc = (plane ? Al : Ah) + (size_t)(rb + m) * K + kc + q * 8;
                ldst = &sA[plane][m * 40 + q * 8];
            } else {
                gsrc = (plane ? Bl : Bh) + (size_t)(nb + m) * K + kc + q * 8;
                ldst = &sB[plane][m * 40 + q * 8];
            }
            *(uint4*)ldst = *(const uint4*)gsrc;
        }
        __syncthreads();
        b16x8 ah[4], al[4], bh[4], bl[4];
        #pragma unroll
        for (int mt = 0; mt < 4; ++mt) {
            int off = (wm * 64 + mt * 16 + lm) * 40 + lq * 8;
            ah[mt] = *(const b16x8*)&sA[0][off];
            al[mt] = *(const b16x8*)&sA[1][off];
        }
        #pragma unroll
        for (int nt = 0; nt < 4; ++nt) {
            int off = (wn * 64 + nt * 16 + lm) * 40 + lq * 8;
            bh[nt] = *(const b16x8*)&sB[0][off];
            bl[nt] = *(const b16x8*)&sB[1][off];
        }
        #pragma unroll
        for (int mt = 0; mt < 4; ++mt)
            #pragma unroll
            for (int nt = 0; nt < 4; ++nt) {
                acc[mt][nt] = __builtin_amdgcn_mfma_f32_16x16x32_bf16(ah[mt], bh[nt], acc[mt][nt], 0, 0, 0);
                acc[mt][nt] = __builtin_amdgcn_mfma_f32_16x16x32_bf16(ah[mt], bl[nt], acc[mt][nt], 0, 0, 0);
                acc[mt][nt] = __builtin_amdgcn_mfma_f32_16x16x32_bf16(al[mt], bh[nt], acc[mt][nt], 0, 0, 0);
            }
    }
    #pragma unroll
    for (int ch = 0; ch < 4; ++ch) {
        __syncthreads();
        if (wm == (ch >> 1)) {
            const int mt0 = (ch & 1) * 2;
            #pragma unroll
            for (int mm = 0; mm < 2; ++mm) {
                #pragma unroll
                for (int nt = 0; nt < 4; ++nt)
                    #pragma unroll
                    for (int rr = 0; rr < 4; ++rr)
                        tile[(mm * 16 + lq * 4 + rr) * 132 + wn * 64 + nt * 16 + lm] =
                            acc[mt0 + mm][nt][rr];
            }
        }
        __syncthreads();
        const int rowbase = rb + ch * 32;
        #pragma unroll
        for (int i = 0; i < 4; ++i) {
            int e = t + i * 256;
            int lr = e >> 5, c4 = (e & 31) * 4;
            *(float4*)&C[(size_t)(rowbase + lr) * N + nb + c4] = *(const float4*)&tile[lr * 132 + c4];
        }
    }
}

// ---------------- fc1: split-bf16 MFMA GEMM + fused max-pool ----------------
__global__ __launch_bounds__(256)
void gemm_fc1_mfma(const unsigned short* __restrict__ Ah, const unsigned short* __restrict__ Al,
                   const unsigned short* __restrict__ Bh, const unsigned short* __restrict__ Bl,
                   const float* __restrict__ bias, unsigned* __restrict__ pool) {
    __shared__ unsigned short sA[2][128 * 40];
    __shared__ unsigned short sB[2][128 * 40];
    const int t = threadIdx.x;
    const int nb = blockIdx.y * 128, mb = blockIdx.x * 128;
    const int w = t >> 6, l = t & 63;
    const int wm = w & 1, wn = w >> 1;
    const int lm = l & 15, lq = l >> 4;

    f32x4 acc[4][4];
    #pragma unroll
    for (int i = 0; i < 4; ++i)
        #pragma unroll
        for (int j = 0; j < 4; ++j) acc[i][j] = (f32x4){0.f, 0.f, 0.f, 0.f};

    for (int kc = 0; kc < 448; kc += 32) {
        __syncthreads();
        #pragma unroll
        for (int i = 0; i < 8; ++i) {
            int c = t + i * 256;
            int idx = c & 511, m = idx >> 2, q = idx & 3;
            int plane = (c >> 9) & 1;
            const unsigned short* gsrc;
            unsigned short* ldst;
            if (c < 1024) {
                gsrc = (plane ? Al : Ah) + (size_t)(mb + m) * 448 + kc + q * 8;
                ldst = &sA[plane][m * 40 + q * 8];
            } else {
                gsrc = (plane ? Bl : Bh) + (size_t)(nb + m) * 448 + kc + q * 8;
                ldst = &sB[plane][m * 40 + q * 8];
            }
            *(uint4*)ldst = *(const uint4*)gsrc;
        }
        __syncthreads();
        b16x8 ah[4], al[4], bh[4], bl[4];
        #pragma unroll
        for (int mt = 0; mt < 4; ++mt) {
            int off = (wm * 64 + mt * 16 + lm) * 40 + lq * 8;
            ah[mt] = *(const b16x8*)&sA[0][off];
            al[mt] = *(const b16x8*)&sA[1][off];
        }
        #pragma unroll
        for (int nt = 0; nt < 4; ++nt) {
            int off = (wn * 64 + nt * 16 + lm) * 40 + lq * 8;
            bh[nt] = *(const b16x8*)&sB[0][off];
            bl[nt] = *(const b16x8*)&sB[1][off];
        }
        #pragma unroll
        for (int mt = 0; mt < 4; ++mt)
            #pragma unroll
            for (int nt = 0; nt < 4; ++nt) {
                acc[mt][nt] = __builtin_amdgcn_mfma_f32_16x16x32_bf16(ah[mt], bh[nt], acc[mt][nt], 0, 0, 0);
                acc[mt][nt] = __builtin_amdgcn_mfma_f32_16x16x32_bf16(ah[mt], bl[nt], acc[mt][nt], 0, 0, 0);
                acc[mt][nt] = __builtin_amdgcn_mfma_f32_16x16x32_bf16(al[mt], bh[nt], acc[mt][nt], 0, 0, 0);
            }
    }
    const int batch = blockIdx.x >> 4;
    #pragma unroll
    for (int nt = 0; nt < 4; ++nt) {
        float m0 = -3.4e38f;
        #pragma unroll
        for (int mt = 0; mt < 4; ++mt)
            #pragma unroll
            for (int rr = 0; rr < 4; ++rr) m0 = fmaxf(m0, acc[mt][nt][rr]);
        m0 = fmaxf(m0, __shfl_xor(m0, 16, 64));
        m0 = fmaxf(m0, __shfl_xor(m0, 32, 64));
        if (l < 16) {
            int col = nb + wn * 64 + nt * 16 + l;
            atomicMax(&pool[batch * 1024 + col], f2o(m0 + bias[col]));
        }
    }
}

// ---------------- edge-conv aggregate ----------------
__global__ void agg_kernel(const float* __restrict__ UV, const int* __restrict__ idx,
                           const float* __restrict__ bias, float* __restrict__ xo, int od) {
    const int p = ((blockIdx.x & 7) << 11) + (blockIdx.x >> 3);
    const int c = threadIdx.x;
    const float u = UV[(size_t)p * 2 * od + c];
    float m = -3.4e38f;
    #pragma unroll
    for (int k = 0; k < KNN; ++k) {
        int j = idx[p * KNN + k];
        m = fmaxf(m, UV[(size_t)j * 2 * od + od + c]);
    }
    xo[(size_t)p * od + c] = u + bias[c] + m;
}

// ---------------- head: split-k GEMM + per-column BN ----------------
template<int IND, int OD, int KSEG, bool UNMAP>
__global__ __launch_bounds__(256)
void head_gemm_k(const float* __restrict__ in, const float* __restrict__ W,
                 float* __restrict__ P) {
    const int KL = IND / KSEG;
    __shared__ float xs[8][IND / KSEG];
    const int t = threadIdx.x;
    const int kb = blockIdx.y * KL;
    const int cb = blockIdx.x * 64;
    for (int e = t; e < 8 * KL; e += 256) {
        int r = e / KL, k = e - r * KL;
        if (UNMAP) xs[r][k] = o2f(((const unsigned*)in)[r * IND + kb + k]);
        else       xs[r][k] = in[r * IND + kb + k];
    }
    __syncthreads();
    const int c = t & 63, rr = t >> 6;
    float a0 = 0.f, a1 = 0.f;
    #pragma unroll 4
    for (int k = 0; k < KL; ++k) {
        float wv = W[(size_t)(kb + k) * OD + cb + c];
        a0 += xs[2 * rr][k] * wv;
        a1 += xs[2 * rr + 1][k] * wv;
    }
    P[(size_t)(blockIdx.y * 8 + 2 * rr) * OD + cb + c]     = a0;
    P[(size_t)(blockIdx.y * 8 + 2 * rr + 1) * OD + cb + c] = a1;
}

template<int OD, int KSEG>
__global__ void head_bn2(const float* __restrict__ P, const float* __restrict__ bias,
                         const float* __restrict__ g, const float* __restrict__ be,
                         float* __restrict__ out) {
    const int c = blockIdx.x * 256 + threadIdx.x;
    float a[8];
    #pragma unroll
    for (int r = 0; r < 8; ++r) {
        float s = bias[c];
        #pragma unroll
        for (int ks = 0; ks < KSEG; ++ks) s += P[(size_t)(ks * 8 + r) * OD + c];
        a[r] = s;
    }
    float mu = 0.f;
    #pragma unroll
    for (int r = 0; r < 8; ++r) mu += a[r];
    mu *= 0.125f;
    float vr = 0.f;
    #pragma unroll
    for (int r = 0; r < 8; ++r) { float d = a[r] - mu; vr += d * d; }
    vr *= 0.125f;
    float is = rsqrtf(vr + 1e-5f) * g[c];
    #pragma unroll
    for (int r = 0; r < 8; ++r)
        out[r * OD + c] = fmaxf(is * (a[r] - mu) + be[c], 0.f);
}

// final Lin [8,256]@[256,23] + log_softmax
__global__ void head3_kernel(const float* __restrict__ x, const float* __restrict__ W,
                             const float* __restrict__ b, float* __restrict__ out) {
    __shared__ float xs[8 * 256];
    __shared__ float lg[8][23];
    __shared__ float red[8][2];
    const int t = threadIdx.x;
    for (int e = t; e < 2048; e += 256) xs[e] = x[e];
    __syncthreads();
    if (t < 184) {
        int r = t / 23, c = t - 23 * r;
        float a = b[c];
        for (int k = 0; k < 256; ++k) a += xs[r * 256 + k] * W[k * 23 + c];
        lg[r][c] = a;
    }
    __syncthreads();
    if (t < 8) {
        float mx = -3.4e38f;
        for (int c = 0; c < 23; ++c) mx = fmaxf(mx, lg[t][c]);
        float s = 0.f;
        for (int c = 0; c < 23; ++c) s += expf(lg[t][c] - mx);
        red[t][0] = mx; red[t][1] = logf(s);
    }
    __syncthreads();
    if (t < 184) {
        int r = t / 23, c = t - 23 * r;
        out[t] = lg[r][c] - red[r][0] - red[r][1];
    }
}

// ---------------- launcher ----------------
extern "C" void kernel_launch(void* const* d_in, const int* in_sizes, int n_in,
                              void* d_out, int out_size, void* d_ws, size_t ws_size,
                              hipStream_t stream) {
    (void)in_sizes; (void)n_in; (void)out_size; (void)ws_size;
    const float* pos = (const float*)d_in[0];
    const float* W1  = (const float*)d_in[2];  const float* b1  = (const float*)d_in[3];
    const float* W2  = (const float*)d_in[4];  const float* b2  = (const float*)d_in[5];
    const float* W3  = (const float*)d_in[6];  const float* b3  = (const float*)d_in[7];
    const float* Wf1 = (const float*)d_in[8];  const float* bf1 = (const float*)d_in[9];
    const float* Wa  = (const float*)d_in[10]; const float* ba  = (const float*)d_in[11];
    const float* ga  = (const float*)d_in[12]; const float* bea = (const float*)d_in[13];
    const float* Wb  = (const float*)d_in[14]; const float* bb  = (const float*)d_in[15];
    const float* gb  = (const float*)d_in[16]; const float* beb = (const float*)d_in[17];
    const float* Wc  = (const float*)d_in[18]; const float* bc  = (const float*)d_in[19];

    char* ws = (char*)d_ws;
    float*    n2   = (float*)(ws + OFF_N2);
    int*      idx  = (int*)(ws + OFF_IDX);
    unsigned* pool = (unsigned*)(ws + OFF_POOL);
    float*    C1   = (float*)(ws + OFF_C1);
    float*    C2   = (float*)(ws + OFF_C2);
    float*    x1   = (float*)(ws + OFF_X1);
    float*    x2   = (float*)(ws + OFF_X2);
    float*    x3   = (float*)(ws + OFF_X3);
    float*    UV   = (float*)(ws + OFF_UV);
    float*    P1   = (float*)(ws + OFF_P1);
    float*    P2   = (float*)(ws + OFF_P2);
    unsigned short* Xph  = (unsigned short*)(ws + OFF_XPH);
    unsigned short* Xpl  = (unsigned short*)(ws + OFF_XPL);
    unsigned short* Apkh = (unsigned short*)(ws + OFF_APKH);
    unsigned short* Apkl = (unsigned short*)(ws + OFF_APKL);
    unsigned short* Bth  = (unsigned short*)(ws + OFF_BTH);
    unsigned short* Btl  = (unsigned short*)(ws + OFF_BTL);
    unsigned short* Wt1h = (unsigned short*)(ws + OFF_WT1H);
    unsigned short* Wt1l = (unsigned short*)(ws + OFF_WT1L);
    unsigned short* Wt2h = (unsigned short*)(ws + OFF_WT2H);
    unsigned short* Wt2l = (unsigned short*)(ws + OFF_WT2L);
    unsigned short* Wt3h = (unsigned short*)(ws + OFF_WT3H);
    unsigned short* Wt3l = (unsigned short*)(ws + OFF_WT3L);

    // prep
    init_pool_kernel<<<32, 256, 0, stream>>>(pool);
    packWt_kernel<<<16,  256, 0, stream>>>(W1, Wt1h, Wt1l, 3,   32,  64);
    packWt_kernel<<<64,  256, 0, stream>>>(W2, Wt2h, Wt2l, 64,  64,  128);
    packWt_kernel<<<256, 256, 0, stream>>>(W3, Wt3h, Wt3l, 128, 128, 256);

    // edge conv 1 (d=3 padded to 32)
    packX0_kernel<<<64, 256, 0, stream>>>(pos, Xph, Xpl, n2);
    knn_fused16_kernel<32><<<1024, 256, 0, stream>>>(Xph, Xpl, n2, idx);
    gemm_uv_mfma<32><<<dim3(128, 1), 256, 0, stream>>>(Xph, Xpl, Wt1h, Wt1l, UV, 128);
    agg_kernel<<<NPTS, 64, 0, stream>>>(UV, idx, b1, x1, 64);

    // edge conv 2 (64 -> 128)
    sqnorm_kernel<64><<<64, 256, 0, stream>>>(x1, n2);
    packX_kernel<<<1024, 256, 0, stream>>>(x1, Xph, Xpl);
    knn_fused16_kernel<64><<<1024, 256, 0, stream>>>(Xph, Xpl, n2, idx);
    gemm_uv_mfma<64><<<dim3(128, 2), 256, 0, stream>>>(Xph, Xpl, Wt2h, Wt2l, UV, 256);
    agg_kernel<<<NPTS, 128, 0, stream>>>(UV, idx, b2, x2, 128);

    // edge conv 3 (128 -> 256)
    sqnorm_kernel<128><<<64, 256, 0, stream>>>(x2, n2);
    packX_kernel<<<2048, 256, 0, stream>>>(x2, Xph, Xpl);
    knn_fused16_kernel<128><<<1024, 256, 0, stream>>>(Xph, Xpl, n2, idx);
    gemm_uv_mfma<128><<<dim3(128, 4), 256, 0, stream>>>(Xph, Xpl, Wt3h, Wt3l, UV, 512);
    agg_kernel<<<NPTS, 256, 0, stream>>>(UV, idx, b3, x3, 256);

    // fc1 (MFMA) + fused max pool
    packA_kernel<<<7168, 256, 0, stream>>>(x1, x2, x3, Apkh, Apkl);
    packB_kernel<<<448,  256, 0, stream>>>(Wf1, Bth, Btl);
    gemm_fc1_mfma<<<dim3(128, 8), 256, 0, stream>>>(Apkh, Apkl, Bth, Btl, bf1, pool);

    // head: split-k GEMM + BN
    head_gemm_k<1024, 512, 8, true ><<<dim3(8, 8), 256, 0, stream>>>((const float*)pool, Wa, P1);
    head_bn2<512, 8><<<2, 256, 0, stream>>>(P1, ba, ga, bea, C1);
    head_gemm_k<512, 256, 4, false><<<dim3(4, 4), 256, 0, stream>>>(C1, Wb, P2);
    head_bn2<256, 4><<<1, 256, 0, stream>>>(P2, bb, gb, beb, C2);
    head3_kernel<<<1, 256, 0, stream>>>(C2, Wc, bc, (float*)d_out);
}

// Round 11
// 835.456 us; speedup vs baseline: 1.3522x; 1.3522x over previous
//
#include <hip/hip_runtime.h>
#include <math.h>

#define NPTS 16384
#define PPB  2048
#define KNN  20

// ---------------- workspace layout (bytes), total 64 MiB ----------------
#define OFF_WT1H  0u
#define OFF_WT1L  8192u
#define OFF_WT2H  16384u
#define OFF_WT2L  49152u
#define OFF_WT3H  81920u
#define OFF_WT3L  212992u
#define OFF_N2    1048576u
#define OFF_IDX   1114112u     // 16384*20*4
#define OFF_POOL  2760704u     // 8192*4
#define OFF_C1    2793472u
#define OFF_C2    2809856u
#define OFF_X1    4194304u     // 16384*64*4  (dead after packA; reused by head partials)
#define OFF_P1    4194304u
#define OFF_P2    4325376u
#define OFF_X2    8388608u     // 16384*128*4
#define OFF_X3    16777216u    // 16384*256*4 (holds X bf16 planes until agg-3 writes x3)
#define OFF_XPH   16777216u
#define OFF_XPL   25165824u
#define OFF_UV    33554432u    // U|V per stage -> packed-A planes for fc1
#define OFF_APKH  33554432u
#define OFF_APKL  48234496u
#define OFF_BTH   0u
#define OFF_BTL   917504u

typedef __attribute__((ext_vector_type(8))) short b16x8;
typedef __attribute__((ext_vector_type(4))) float f32x4;

__device__ __forceinline__ unsigned f2o(float f) {
    unsigned u = __float_as_uint(f);
    return (u & 0x80000000u) ? ~u : (u | 0x80000000u);
}
__device__ __forceinline__ float o2f(unsigned u) {
    return (u & 0x80000000u) ? __uint_as_float(u & 0x7fffffffu) : __uint_as_float(~u);
}

// split fp32 -> (hi, lo) bf16 pair, RNE both; x ~= hi + lo to ~2^-18 rel
__device__ __forceinline__ void split_bf16(float x, unsigned short& h, unsigned short& l) {
    unsigned u = __float_as_uint(x);
    unsigned rh = (u + 0x7fffu + ((u >> 16) & 1u)) & 0xffff0000u;
    h = (unsigned short)(rh >> 16);
    float r = x - __uint_as_float(rh);
    unsigned v = __float_as_uint(r);
    l = (unsigned short)((v + 0x7fffu + ((v >> 16) & 1u)) >> 16);
}

// register top-20 insert (R0/R8-verified): replace worst slot, rescan for new worst
__device__ __forceinline__ void topk_insert(float (&bd)[KNN], int (&bi)[KNN],
                                            float& worst, int& wslot, float v, int q) {
    #pragma unroll
    for (int s = 0; s < KNN; ++s) if (s == wslot) { bd[s] = v; bi[s] = q; }
    float w = bd[0]; int sl = 0;
    #pragma unroll
    for (int s = 1; s < KNN; ++s) if (bd[s] > w) { w = bd[s]; sl = s; }
    worst = w; wslot = sl;
}

// ---------------- prep kernels ----------------
__global__ void init_pool_kernel(unsigned* __restrict__ pool) {
    pool[blockIdx.x * 256 + threadIdx.x] = 0u;
}

template<int D>
__global__ void sqnorm_kernel(const float* __restrict__ X, float* __restrict__ n2) {
    int p = blockIdx.x * 256 + threadIdx.x;
    float s = 0.f;
    #pragma unroll
    for (int k = 0; k < D; k += 4) {
        float4 v = *(const float4*)&X[(size_t)p * D + k];
        s += v.x * v.x + v.y * v.y + v.z * v.z + v.w * v.w;
    }
    n2[p] = s;
}

// stage-1: pos [16384][3] -> bf16 hi/lo planes [16384][32] (cols 3..31 zero) + n2
__global__ void packX0_kernel(const float* __restrict__ pos,
                              unsigned short* __restrict__ Xh, unsigned short* __restrict__ Xl,
                              float* __restrict__ n2) {
    int p = blockIdx.x * 256 + threadIdx.x;
    float x = pos[p * 3 + 0], y = pos[p * 3 + 1], z = pos[p * 3 + 2];
    n2[p] = x * x + y * y + z * z;
    ushort4 h = {0, 0, 0, 0}, l = {0, 0, 0, 0};
    split_bf16(x, h.x, l.x); split_bf16(y, h.y, l.y); split_bf16(z, h.z, l.z);
    ushort4 zed = {0, 0, 0, 0};
    *(ushort4*)&Xh[(size_t)p * 32] = h;
    *(ushort4*)&Xl[(size_t)p * 32] = l;
    #pragma unroll
    for (int c = 4; c < 32; c += 4) {
        *(ushort4*)&Xh[(size_t)p * 32 + c] = zed;
        *(ushort4*)&Xl[(size_t)p * 32 + c] = zed;
    }
}

// pack X [16384 x K] fp32 -> bf16 hi/lo planes
__global__ void packX_kernel(const float* __restrict__ X,
                             unsigned short* __restrict__ Xh, unsigned short* __restrict__ Xl) {
    int e = blockIdx.x * 256 + threadIdx.x;
    float4 v = *(const float4*)&X[4 * (size_t)e];
    ushort4 h, l;
    split_bf16(v.x, h.x, l.x); split_bf16(v.y, h.y, l.y);
    split_bf16(v.z, h.z, l.z); split_bf16(v.w, h.w, l.w);
    *(ushort4*)&Xh[4 * (size_t)e] = h;
    *(ushort4*)&Xl[4 * (size_t)e] = l;
}

// W [2d][od] -> W^T hi/lo planes [2od][dpad]: n<od: U = W_top - W_bot; else V = W_bot
__global__ void packWt_kernel(const float* __restrict__ W,
                              unsigned short* __restrict__ Bh, unsigned short* __restrict__ Bl,
                              int d, int dpad, int od) {
    int e = blockIdx.x * 256 + threadIdx.x;
    int n = e / dpad, k = e - n * dpad;
    float v = 0.f;
    if (k < d) v = (n < od) ? (W[k * od + n] - W[(d + k) * od + n])
                            : W[(d + k) * od + (n - od)];
    unsigned short h, l;
    split_bf16(v, h, l);
    Bh[e] = h; Bl[e] = l;
}

// pack A = concat(x1,x2,x3) [16384 x 448] into bf16 hi/lo planes
__global__ void packA_kernel(const float* __restrict__ x1, const float* __restrict__ x2,
                             const float* __restrict__ x3,
                             unsigned short* __restrict__ Ah, unsigned short* __restrict__ Al) {
    int e = blockIdx.x * 256 + threadIdx.x;
    int m = e / 112, c4 = (e - m * 112) * 4;
    float4 v;
    if (c4 < 64)       v = *(const float4*)&x1[(size_t)m * 64 + c4];
    else if (c4 < 192) v = *(const float4*)&x2[(size_t)m * 128 + (c4 - 64)];
    else               v = *(const float4*)&x3[(size_t)m * 256 + (c4 - 192)];
    ushort4 h, l;
    split_bf16(v.x, h.x, l.x); split_bf16(v.y, h.y, l.y);
    split_bf16(v.z, h.z, l.z); split_bf16(v.w, h.w, l.w);
    *(ushort4*)&Ah[(size_t)m * 448 + c4] = h;
    *(ushort4*)&Al[(size_t)m * 448 + c4] = l;
}

// pack Wf1^T [1024 x 448] into bf16 hi/lo planes
__global__ void packB_kernel(const float* __restrict__ Wf1,
                             unsigned short* __restrict__ Bh, unsigned short* __restrict__ Bl) {
    int e = blockIdx.x * 256 + threadIdx.x;
    int n = e / 112, k4 = (e - n * 112) * 4;
    ushort4 h, l;
    float v0 = Wf1[(size_t)(k4 + 0) * 1024 + n];
    float v1 = Wf1[(size_t)(k4 + 1) * 1024 + n];
    float v2 = Wf1[(size_t)(k4 + 2) * 1024 + n];
    float v3 = Wf1[(size_t)(k4 + 3) * 1024 + n];
    split_bf16(v0, h.x, l.x); split_bf16(v1, h.y, l.y);
    split_bf16(v2, h.z, l.z); split_bf16(v3, h.w, l.w);
    *(ushort4*)&Bh[(size_t)n * 448 + k4] = h;
    *(ushort4*)&Bl[(size_t)n * 448 + k4] = l;
}

// ---------------- fused kNN v4: R8 geometry + EXACT row-threshold filter ----------------
// block: 32 rows x 2048 candidates, 16 chunks of 128. Select: 8 threads/row, 16 vals
// per thread per chunk. Each lane keeps sorted top-3 of its stream; tau = max over
// row's 8 lanes of lane-3rd-best >= row 24th-smallest => passes every final-top-20
// member (exact, float compares, no truncation). Insert guarded by (v<=tau && v<worst)
// fires ~16x/thread total instead of ~71x.
template<int K>
__global__ __launch_bounds__(256)
void knn_fused_v4(const unsigned short* __restrict__ Xh, const unsigned short* __restrict__ Xl,
                  const float* __restrict__ n2, int* __restrict__ idxout) {
    __shared__ __align__(16) unsigned char smem[42496];
    unsigned short (*sA)[1280] = (unsigned short (*)[1280])smem;             // [2][32*40]
    unsigned short (*sB)[5120] = (unsigned short (*)[5120])(smem + 5120);    // [2][128*40]
    float* Ds = (float*)(smem + 25600);                                      // 32 x 132

    const int t = threadIdx.x;
    const int rb = blockIdx.x * 32;
    const int qbase = (rb >> 11) << 11;             // batch-local candidates
    const int w = t >> 6, l = t & 63;
    const int lm = l & 15, lq = l >> 4;
    const int r = t >> 3, sub = t & 7;              // select mapping: 8 threads/row

    float bd[KNN]; int bi[KNN];
    #pragma unroll
    for (int s = 0; s < KNN; ++s) { bd[s] = 3.0e38f; bi[s] = 0; }
    float worst = 3.0e38f; int wslot = 0;
    float k1 = 3.2e38f, k2 = 3.2e38f, k3 = 3.2e38f; // lane top-3 (k1<=k2<=k3)

    for (int qt = 0; qt < 16; ++qt) {
        const int qb = qbase + qt * 128;
        f32x4 acc[2][2];
        #pragma unroll
        for (int i = 0; i < 2; ++i)
            #pragma unroll
            for (int j = 0; j < 2; ++j) acc[i][j] = (f32x4){0.f, 0.f, 0.f, 0.f};

        for (int kc = 0; kc < K; kc += 32) {
            __syncthreads();                        // sB consumers done
            #pragma unroll
            for (int i = 0; i < 5; ++i) {           // 1280 16B chunks: A 256, B 1024
                int c = t + i * 256;
                const unsigned short* gsrc;
                unsigned short* ldst;
                if (c < 256) {
                    int idx = c & 127, m = idx >> 2, q = idx & 3;
                    int plane = (c >> 7) & 1;
                    gsrc = (plane ? Xl : Xh) + (size_t)(rb + m) * K + kc + q * 8;
                    ldst = &sA[plane][m * 40 + q * 8];
                } else {
                    int c2 = c - 256;
                    int idx = c2 & 511, m = idx >> 2, q = idx & 3;
                    int plane = c2 >> 9;
                    gsrc = (plane ? Xl : Xh) + (size_t)(qb + m) * K + kc + q * 8;
                    ldst = &sB[plane][m * 40 + q * 8];
                }
                *(uint4*)ldst = *(const uint4*)gsrc;
            }
            __syncthreads();
            b16x8 ah[2], al[2], bh[2], bl[2];
            #pragma unroll
            for (int rt = 0; rt < 2; ++rt) {
                int off = (rt * 16 + lm) * 40 + lq * 8;
                ah[rt] = *(const b16x8*)&sA[0][off];
                al[rt] = *(const b16x8*)&sA[1][off];
            }
            #pragma unroll
            for (int ct = 0; ct < 2; ++ct) {
                int off = (w * 32 + ct * 16 + lm) * 40 + lq * 8;
                bh[ct] = *(const b16x8*)&sB[0][off];
                bl[ct] = *(const b16x8*)&sB[1][off];
            }
            #pragma unroll
            for (int rt = 0; rt < 2; ++rt)
                #pragma unroll
                for (int ct = 0; ct < 2; ++ct) {
                    acc[rt][ct] = __builtin_amdgcn_mfma_f32_16x16x32_bf16(ah[rt], bh[ct], acc[rt][ct], 0, 0, 0);
                    acc[rt][ct] = __builtin_amdgcn_mfma_f32_16x16x32_bf16(ah[rt], bl[ct], acc[rt][ct], 0, 0, 0);
                    acc[rt][ct] = __builtin_amdgcn_mfma_f32_16x16x32_bf16(al[rt], bh[ct], acc[rt][ct], 0, 0, 0);
                }
        }
        float nv[2];
        #pragma unroll
        for (int ct = 0; ct < 2; ++ct) nv[ct] = n2[qb + w * 32 + ct * 16 + lm];
        __syncthreads();                            // prev select done reading Ds
        #pragma unroll
        for (int rt = 0; rt < 2; ++rt)
            #pragma unroll
            for (int ct = 0; ct < 2; ++ct)
                #pragma unroll
                for (int rr = 0; rr < 4; ++rr)
                    Ds[(rt * 16 + lq * 4 + rr) * 132 + w * 32 + ct * 16 + lm] =
                        nv[ct] - 2.f * acc[rt][ct][rr];
        __syncthreads();
        // pass A: load 16 values, update lane top-3 (cheap, branch-light)
        float vv[16];
        #pragma unroll
        for (int g = 0; g < 4; ++g) {
            float4 v = *(const float4*)&Ds[r * 132 + 16 * sub + 4 * g];
            vv[4 * g + 0] = v.x; vv[4 * g + 1] = v.y;
            vv[4 * g + 2] = v.z; vv[4 * g + 3] = v.w;
        }
        #pragma unroll
        for (int j = 0; j < 16; ++j) {
            float v = vv[j];
            if (v < k3) {
                if (v < k1)      { k3 = k2; k2 = k1; k1 = v; }
                else if (v < k2) { k3 = k2; k2 = v; }
                else               k3 = v;
            }
        }
        // tau = max over the row's 8 lanes of lane-3rd-best  (>= row 24th-smallest)
        float tau = k3;
        #pragma unroll
        for (int m = 1; m < 8; m <<= 1) tau = fmaxf(tau, __shfl_xor(tau, m, 64));
        // pass B: filtered exact insert (rare)
        const int q0 = qt * 128 + 16 * sub;
        #pragma unroll
        for (int j = 0; j < 16; ++j) {
            float v = vv[j];
            if (v <= tau && v < worst) topk_insert(bd, bi, worst, wslot, v, q0 + j);
        }
    }

    // merge 8 register lists of 20 -> top-20 per row (R8-verified pattern)
    __syncthreads();
    int* DsI = (int*)Ds;                            // row stride 132 ints
    float mv = 3.3e38f; int mq = 1 << 20, mj = 0;
    #pragma unroll
    for (int s = 0; s < KNN; ++s) {
        float x = bd[s]; int q = bi[s];
        if (x < mv || (x == mv && q < mq)) { mv = x; mq = q; mj = s; }
    }
    for (int round = 0; round < KNN; ++round) {
        float rv = mv; int rq = mq;
        #pragma unroll
        for (int m = 1; m < 8; m <<= 1) {
            float ov = __shfl_xor(rv, m, 64);
            int   oq = __shfl_xor(rq, m, 64);
            if (ov < rv || (ov == rv && oq < rq)) { rv = ov; rq = oq; }
        }
        if (sub == 0) DsI[r * 132 + round] = rq;
        if (mv == rv && mq == rq) {                 // I own the winner: consume + rescan
            #pragma unroll
            for (int s = 0; s < KNN; ++s) if (s == mj) bd[s] = 3.3e38f;
            mv = 3.3e38f; mq = 1 << 20; mj = 0;
            #pragma unroll
            for (int s = 0; s < KNN; ++s) {
                float x = bd[s]; int q = bi[s];
                if (x < mv || (x == mv && q < mq)) { mv = x; mq = q; mj = s; }
            }
        }
    }
    // same-wave visibility within each 8-lane row group: no barrier needed
    for (int s = sub; s < KNN; s += 8)
        idxout[(size_t)(rb + r) * KNN + s] = qbase + DsI[r * 132 + s];
}

// ---------------- UV projection: split-bf16 MFMA (all stages) ----------------
template<int K>
__global__ __launch_bounds__(256)
void gemm_uv_mfma(const unsigned short* __restrict__ Ah, const unsigned short* __restrict__ Al,
                  const unsigned short* __restrict__ Bh, const unsigned short* __restrict__ Bl,
                  float* __restrict__ C, int N) {
    __shared__ __align__(16) unsigned char smem[40960];
    unsigned short (*sA)[5120] = (unsigned short (*)[5120])smem;
    unsigned short (*sB)[5120] = (unsigned short (*)[5120])(smem + 20480);
    float* tile = (float*)smem;

    const int t = threadIdx.x;
    const int rb = blockIdx.x * 128, nb = blockIdx.y * 128;
    const int w = t >> 6, l = t & 63;
    const int wm = w & 1, wn = w >> 1;
    const int lm = l & 15, lq = l >> 4;

    f32x4 acc[4][4];
    #pragma unroll
    for (int i = 0; i < 4; ++i)
        #pragma unroll
        for (int j = 0; j < 4; ++j) acc[i][j] = (f32x4){0.f, 0.f, 0.f, 0.f};

    for (int kc = 0; kc < K; kc += 32) {
        __syncthreads();
        #pragma unroll
        for (int i = 0; i < 8; ++i) {
            int c = t + i * 256;
            int idx = c & 511, m = idx >> 2, q = idx & 3;
            int plane = (c >> 9) & 1;
            const unsigned short* gsrc;
            unsigned short* ldst;
            if (c < 1024) {
                gsrc = (plane ? Al : Ah) + (size_t)(rb + m) * K + kc + q * 8;
                ldst = &sA[plane][m * 40 + q * 8];
            } else {
                gsrc = (plane ? Bl : Bh) + (size_t)(nb + m) * K + kc + q * 8;
                ldst = &sB[plane][m * 40 + q * 8];
            }
            *(uint4*)ldst = *(const uint4*)gsrc;
        }
        __syncthreads();
        b16x8 ah[4], al[4], bh[4], bl[4];
        #pragma unroll
        for (int mt = 0; mt < 4; ++mt) {
            int off = (wm * 64 + mt * 16 + lm) * 40 + lq * 8;
            ah[mt] = *(const b16x8*)&sA[0][off];
            al[mt] = *(const b16x8*)&sA[1][off];
        }
        #pragma unroll
        for (int nt = 0; nt < 4; ++nt) {
            int off = (wn * 64 + nt * 16 + lm) * 40 + lq * 8;
            bh[nt] = *(const b16x8*)&sB[0][off];
            bl[nt] = *(const b16x8*)&sB[1][off];
        }
        #pragma unroll
        for (int mt = 0; mt < 4; ++mt)
            #pragma unroll
            for (int nt = 0; nt < 4; ++nt) {
                acc[mt][nt] = __builtin_amdgcn_mfma_f32_16x16x32_bf16(ah[mt], bh[nt], acc[mt][nt], 0, 0, 0);
                acc[mt][nt] = __builtin_amdgcn_mfma_f32_16x16x32_bf16(ah[mt], bl[nt], acc[mt][nt], 0, 0, 0);
                acc[mt][nt] = __builtin_amdgcn_mfma_f32_16x16x32_bf16(al[mt], bh[nt], acc[mt][nt], 0, 0, 0);
            }
    }
    #pragma unroll
    for (int ch = 0; ch < 4; ++ch) {
        __syncthreads();
        if (wm == (ch >> 1)) {
            const int mt0 = (ch & 1) * 2;
            #pragma unroll
            for (int mm = 0; mm < 2; ++mm) {
                #pragma unroll
                for (int nt = 0; nt < 4; ++nt)
                    #pragma unroll
                    for (int rr = 0; rr < 4; ++rr)
                        tile[(mm * 16 + lq * 4 + rr) * 132 + wn * 64 + nt * 16 + lm] =
                            acc[mt0 + mm][nt][rr];
            }
        }
        __syncthreads();
        const int rowbase = rb + ch * 32;
        #pragma unroll
        for (int i = 0; i < 4; ++i) {
            int e = t + i * 256;
            int lr = e >> 5, c4 = (e & 31) * 4;
            *(float4*)&C[(size_t)(rowbase + lr) * N + nb + c4] = *(const float4*)&tile[lr * 132 + c4];
        }
    }
}

// ---------------- fc1: split-bf16 MFMA GEMM + fused max-pool ----------------
__global__ __launch_bounds__(256)
void gemm_fc1_mfma(const unsigned short* __restrict__ Ah, const unsigned short* __restrict__ Al,
                   const unsigned short* __restrict__ Bh, const unsigned short* __restrict__ Bl,
                   const float* __restrict__ bias, unsigned* __restrict__ pool) {
    __shared__ unsigned short sA[2][128 * 40];
    __shared__ unsigned short sB[2][128 * 40];
    const int t = threadIdx.x;
    const int nb = blockIdx.y * 128, mb = blockIdx.x * 128;
    const int w = t >> 6, l = t & 63;
    const int wm = w & 1, wn = w >> 1;
    const int lm = l & 15, lq = l >> 4;

    f32x4 acc[4][4];
    #pragma unroll
    for (int i = 0; i < 4; ++i)
        #pragma unroll
        for (int j = 0; j < 4; ++j) acc[i][j] = (f32x4){0.f, 0.f, 0.f, 0.f};

    for (int kc = 0; kc < 448; kc += 32) {
        __syncthreads();
        #pragma unroll
        for (int i = 0; i < 8; ++i) {
            int c = t + i * 256;
            int idx = c & 511, m = idx >> 2, q = idx & 3;
            int plane = (c >> 9) & 1;
            const unsigned short* gsrc;
            unsigned short* ldst;
            if (c < 1024) {
                gsrc = (plane ? Al : Ah) + (size_t)(mb + m) * 448 + kc + q * 8;
                ldst = &sA[plane][m * 40 + q * 8];
            } else {
                gsrc = (plane ? Bl : Bh) + (size_t)(nb + m) * 448 + kc + q * 8;
                ldst = &sB[plane][m * 40 + q * 8];
            }
            *(uint4*)ldst = *(const uint4*)gsrc;
        }
        __syncthreads();
        b16x8 ah[4], al[4], bh[4], bl[4];
        #pragma unroll
        for (int mt = 0; mt < 4; ++mt) {
            int off = (wm * 64 + mt * 16 + lm) * 40 + lq * 8;
            ah[mt] = *(const b16x8*)&sA[0][off];
            al[mt] = *(const b16x8*)&sA[1][off];
        }
        #pragma unroll
        for (int nt = 0; nt < 4; ++nt) {
            int off = (wn * 64 + nt * 16 + lm) * 40 + lq * 8;
            bh[nt] = *(const b16x8*)&sB[0][off];
            bl[nt] = *(const b16x8*)&sB[1][off];
        }
        #pragma unroll
        for (int mt = 0; mt < 4; ++mt)
            #pragma unroll
            for (int nt = 0; nt < 4; ++nt) {
                acc[mt][nt] = __builtin_amdgcn_mfma_f32_16x16x32_bf16(ah[mt], bh[nt], acc[mt][nt], 0, 0, 0);
                acc[mt][nt] = __builtin_amdgcn_mfma_f32_16x16x32_bf16(ah[mt], bl[nt], acc[mt][nt], 0, 0, 0);
                acc[mt][nt] = __builtin_amdgcn_mfma_f32_16x16x32_bf16(al[mt], bh[nt], acc[mt][nt], 0, 0, 0);
            }
    }
    const int batch = blockIdx.x >> 4;
    #pragma unroll
    for (int nt = 0; nt < 4; ++nt) {
        float m0 = -3.4e38f;
        #pragma unroll
        for (int mt = 0; mt < 4; ++mt)
            #pragma unroll
            for (int rr = 0; rr < 4; ++rr) m0 = fmaxf(m0, acc[mt][nt][rr]);
        m0 = fmaxf(m0, __shfl_xor(m0, 16, 64));
        m0 = fmaxf(m0, __shfl_xor(m0, 32, 64));
        if (l < 16) {
            int col = nb + wn * 64 + nt * 16 + l;
            atomicMax(&pool[batch * 1024 + col], f2o(m0 + bias[col]));
        }
    }
}

// ---------------- edge-conv aggregate ----------------
__global__ void agg_kernel(const float* __restrict__ UV, const int* __restrict__ idx,
                           const float* __restrict__ bias, float* __restrict__ xo, int od) {
    const int p = ((blockIdx.x & 7) << 11) + (blockIdx.x >> 3);
    const int c = threadIdx.x;
    const float u = UV[(size_t)p * 2 * od + c];
    float m = -3.4e38f;
    #pragma unroll
    for (int k = 0; k < KNN; ++k) {
        int j = idx[p * KNN + k];
        m = fmaxf(m, UV[(size_t)j * 2 * od + od + c]);
    }
    xo[(size_t)p * od + c] = u + bias[c] + m;
}

// ---------------- head: split-k GEMM + per-column BN ----------------
template<int IND, int OD, int KSEG, bool UNMAP>
__global__ __launch_bounds__(256)
void head_gemm_k(const float* __restrict__ in, const float* __restrict__ W,
                 float* __restrict__ P) {
    const int KL = IND / KSEG;
    __shared__ float xs[8][IND / KSEG];
    const int t = threadIdx.x;
    const int kb = blockIdx.y * KL;
    const int cb = blockIdx.x * 64;
    for (int e = t; e < 8 * KL; e += 256) {
        int r = e / KL, k = e - r * KL;
        if (UNMAP) xs[r][k] = o2f(((const unsigned*)in)[r * IND + kb + k]);
        else       xs[r][k] = in[r * IND + kb + k];
    }
    __syncthreads();
    const int c = t & 63, rr = t >> 6;
    float a0 = 0.f, a1 = 0.f;
    #pragma unroll 4
    for (int k = 0; k < KL; ++k) {
        float wv = W[(size_t)(kb + k) * OD + cb + c];
        a0 += xs[2 * rr][k] * wv;
        a1 += xs[2 * rr + 1][k] * wv;
    }
    P[(size_t)(blockIdx.y * 8 + 2 * rr) * OD + cb + c]     = a0;
    P[(size_t)(blockIdx.y * 8 + 2 * rr + 1) * OD + cb + c] = a1;
}

template<int OD, int KSEG>
__global__ void head_bn2(const float* __restrict__ P, const float* __restrict__ bias,
                         const float* __restrict__ g, const float* __restrict__ be,
                         float* __restrict__ out) {
    const int c = blockIdx.x * 256 + threadIdx.x;
    float a[8];
    #pragma unroll
    for (int r = 0; r < 8; ++r) {
        float s = bias[c];
        #pragma unroll
        for (int ks = 0; ks < KSEG; ++ks) s += P[(size_t)(ks * 8 + r) * OD + c];
        a[r] = s;
    }
    float mu = 0.f;
    #pragma unroll
    for (int r = 0; r < 8; ++r) mu += a[r];
    mu *= 0.125f;
    float vr = 0.f;
    #pragma unroll
    for (int r = 0; r < 8; ++r) { float d = a[r] - mu; vr += d * d; }
    vr *= 0.125f;
    float is = rsqrtf(vr + 1e-5f) * g[c];
    #pragma unroll
    for (int r = 0; r < 8; ++r)
        out[r * OD + c] = fmaxf(is * (a[r] - mu) + be[c], 0.f);
}

// final Lin [8,256]@[256,23] + log_softmax
__global__ void head3_kernel(const float* __restrict__ x, const float* __restrict__ W,
                             const float* __restrict__ b, float* __restrict__ out) {
    __shared__ float xs[8 * 256];
    __shared__ float lg[8][23];
    __shared__ float red[8][2];
    const int t = threadIdx.x;
    for (int e = t; e < 2048; e += 256) xs[e] = x[e];
    __syncthreads();
    if (t < 184) {
        int r = t / 23, c = t - 23 * r;
        float a = b[c];
        for (int k = 0; k < 256; ++k) a += xs[r * 256 + k] * W[k * 23 + c];
        lg[r][c] = a;
    }
    __syncthreads();
    if (t < 8) {
        float mx = -3.4e38f;
        for (int c = 0; c < 23; ++c) mx = fmaxf(mx, lg[t][c]);
        float s = 0.f;
        for (int c = 0; c < 23; ++c) s += expf(lg[t][c] - mx);
        red[t][0] = mx; red[t][1] = logf(s);
    }
    __syncthreads();
    if (t < 184) {
        int r = t / 23, c = t - 23 * r;
        out[t] = lg[r][c] - red[r][0] - red[r][1];
    }
}

// ---------------- launcher ----------------
extern "C" void kernel_launch(void* const* d_in, const int* in_sizes, int n_in,
                              void* d_out, int out_size, void* d_ws, size_t ws_size,
                              hipStream_t stream) {
    (void)in_sizes; (void)n_in; (void)out_size; (void)ws_size;
    const float* pos = (const float*)d_in[0];
    const float* W1  = (const float*)d_in[2];  const float* b1  = (const float*)d_in[3];
    const float* W2  = (const float*)d_in[4];  const float* b2  = (const float*)d_in[5];
    const float* W3  = (const float*)d_in[6];  const float* b3  = (const float*)d_in[7];
    const float* Wf1 = (const float*)d_in[8];  const float* bf1 = (const float*)d_in[9];
    const float* Wa  = (const float*)d_in[10]; const float* ba  = (const float*)d_in[11];
    const float* ga  = (const float*)d_in[12]; const float* bea = (const float*)d_in[13];
    const float* Wb  = (const float*)d_in[14]; const float* bb  = (const float*)d_in[15];
    const float* gb  = (const float*)d_in[16]; const float* beb = (const float*)d_in[17];
    const float* Wc  = (const float*)d_in[18]; const float* bc  = (const float*)d_in[19];

    char* ws = (char*)d_ws;
    float*    n2   = (float*)(ws + OFF_N2);
    int*      idx  = (int*)(ws + OFF_IDX);
    unsigned* pool = (unsigned*)(ws + OFF_POOL);
    float*    C1   = (float*)(ws + OFF_C1);
    float*    C2   = (float*)(ws + OFF_C2);
    float*    x1   = (float*)(ws + OFF_X1);
    float*    x2   = (float*)(ws + OFF_X2);
    float*    x3   = (float*)(ws + OFF_X3);
    float*    UV   = (float*)(ws + OFF_UV);
    float*    P1   = (float*)(ws + OFF_P1);
    float*    P2   = (float*)(ws + OFF_P2);
    unsigned short* Xph  = (unsigned short*)(ws + OFF_XPH);
    unsigned short* Xpl  = (unsigned short*)(ws + OFF_XPL);
    unsigned short* Apkh = (unsigned short*)(ws + OFF_APKH);
    unsigned short* Apkl = (unsigned short*)(ws + OFF_APKL);
    unsigned short* Bth  = (unsigned short*)(ws + OFF_BTH);
    unsigned short* Btl  = (unsigned short*)(ws + OFF_BTL);
    unsigned short* Wt1h = (unsigned short*)(ws + OFF_WT1H);
    unsigned short* Wt1l = (unsigned short*)(ws + OFF_WT1L);
    unsigned short* Wt2h = (unsigned short*)(ws + OFF_WT2H);
    unsigned short* Wt2l = (unsigned short*)(ws + OFF_WT2L);
    unsigned short* Wt3h = (unsigned short*)(ws + OFF_WT3H);
    unsigned short* Wt3l = (unsigned short*)(ws + OFF_WT3L);

    // prep
    init_pool_kernel<<<32, 256, 0, stream>>>(pool);
    packWt_kernel<<<16,  256, 0, stream>>>(W1, Wt1h, Wt1l, 3,   32,  64);
    packWt_kernel<<<64,  256, 0, stream>>>(W2, Wt2h, Wt2l, 64,  64,  128);
    packWt_kernel<<<256, 256, 0, stream>>>(W3, Wt3h, Wt3l, 128, 128, 256);

    // edge conv 1 (d=3 padded to 32)
    packX0_kernel<<<64, 256, 0, stream>>>(pos, Xph, Xpl, n2);
    knn_fused_v4<32><<<512, 256, 0, stream>>>(Xph, Xpl, n2, idx);
    gemm_uv_mfma<32><<<dim3(128, 1), 256, 0, stream>>>(Xph, Xpl, Wt1h, Wt1l, UV, 128);
    agg_kernel<<<NPTS, 64, 0, stream>>>(UV, idx, b1, x1, 64);

    // edge conv 2 (64 -> 128)
    sqnorm_kernel<64><<<64, 256, 0, stream>>>(x1, n2);
    packX_kernel<<<1024, 256, 0, stream>>>(x1, Xph, Xpl);
    knn_fused_v4<64><<<512, 256, 0, stream>>>(Xph, Xpl, n2, idx);
    gemm_uv_mfma<64><<<dim3(128, 2), 256, 0, stream>>>(Xph, Xpl, Wt2h, Wt2l, UV, 256);
    agg_kernel<<<NPTS, 128, 0, stream>>>(UV, idx, b2, x2, 128);

    // edge conv 3 (128 -> 256)
    sqnorm_kernel<128><<<64, 256, 0, stream>>>(x2, n2);
    packX_kernel<<<2048, 256, 0, stream>>>(x2, Xph, Xpl);
    knn_fused_v4<128><<<512, 256, 0, stream>>>(Xph, Xpl, n2, idx);
    gemm_uv_mfma<128><<<dim3(128, 4), 256, 0, stream>>>(Xph, Xpl, Wt3h, Wt3l, UV, 512);
    agg_kernel<<<NPTS, 256, 0, stream>>>(UV, idx, b3, x3, 256);

    // fc1 (MFMA) + fused max pool
    packA_kernel<<<7168, 256, 0, stream>>>(x1, x2, x3, Apkh, Apkl);
    packB_kernel<<<448,  256, 0, stream>>>(Wf1, Bth, Btl);
    gemm_fc1_mfma<<<dim3(128, 8), 256, 0, stream>>>(Apkh, Apkl, Bth, Btl, bf1, pool);

    // head: split-k GEMM + BN
    head_gemm_k<1024, 512, 8, true ><<<dim3(8, 8), 256, 0, stream>>>((const float*)pool, Wa, P1);
    head_bn2<512, 8><<<2, 256, 0, stream>>>(P1, ba, ga, bea, C1);
    head_gemm_k<512, 256, 4, false><<<dim3(4, 4), 256, 0, stream>>>(C1, Wb, P2);
    head_bn2<256, 4><<<1, 256, 0, stream>>>(P2, bb, gb, beb, C2);
    head3_kernel<<<1, 256, 0, stream>>>(C2, Wc, bc, (float*)d_out);
}

// Round 12
// 656.499 us; speedup vs baseline: 1.7208x; 1.2726x over previous
//
#include <hip/hip_runtime.h>
#include <math.h>

#define NPTS 16384
#define PPB  2048
#define KNN  20

// ---------------- workspace layout (bytes), total 64 MiB ----------------
#define OFF_WT1H  0u
#define OFF_WT1L  8192u
#define OFF_WT2H  16384u
#define OFF_WT2L  49152u
#define OFF_WT3H  81920u
#define OFF_WT3L  212992u
#define OFF_N2    1048576u
#define OFF_IDX   1114112u     // 16384*20*4
#define OFF_POOL  2760704u     // 8192*4
#define OFF_C1    2793472u
#define OFF_C2    2809856u
#define OFF_X1    4194304u     // 16384*64*4  (dead after packA; reused by head partials)
#define OFF_P1    4194304u
#define OFF_P2    4325376u
#define OFF_X2    8388608u     // 16384*128*4
#define OFF_X3    16777216u    // 16384*256*4 (holds X bf16 planes until agg-3 writes x3)
#define OFF_XPH   16777216u
#define OFF_XPL   25165824u
#define OFF_UV    33554432u    // U|V per stage -> packed-A planes for fc1
#define OFF_APKH  33554432u
#define OFF_APKL  48234496u
#define OFF_BTH   0u
#define OFF_BTL   917504u

typedef __attribute__((ext_vector_type(8))) short b16x8;
typedef __attribute__((ext_vector_type(4))) float f32x4;

__device__ __forceinline__ unsigned f2o(float f) {
    unsigned u = __float_as_uint(f);
    return (u & 0x80000000u) ? ~u : (u | 0x80000000u);
}
__device__ __forceinline__ float o2f(unsigned u) {
    return (u & 0x80000000u) ? __uint_as_float(u & 0x7fffffffu) : __uint_as_float(~u);
}

// split fp32 -> (hi, lo) bf16 pair, RNE both; x ~= hi + lo to ~2^-18 rel
__device__ __forceinline__ void split_bf16(float x, unsigned short& h, unsigned short& l) {
    unsigned u = __float_as_uint(x);
    unsigned rh = (u + 0x7fffu + ((u >> 16) & 1u)) & 0xffff0000u;
    h = (unsigned short)(rh >> 16);
    float r = x - __uint_as_float(rh);
    unsigned v = __float_as_uint(r);
    l = (unsigned short)((v + 0x7fffu + ((v >> 16) & 1u)) >> 16);
}

// register top-20 insert (R0/R8-verified): replace worst slot, rescan for new worst
__device__ __forceinline__ void topk_insert(float (&bd)[KNN], int (&bi)[KNN],
                                            float& worst, int& wslot, float v, int q) {
    #pragma unroll
    for (int s = 0; s < KNN; ++s) if (s == wslot) { bd[s] = v; bi[s] = q; }
    float w = bd[0]; int sl = 0;
    #pragma unroll
    for (int s = 1; s < KNN; ++s) if (bd[s] > w) { w = bd[s]; sl = s; }
    worst = w; wslot = sl;
}

// ---------------- prep kernels ----------------
__global__ void init_pool_kernel(unsigned* __restrict__ pool) {
    pool[blockIdx.x * 256 + threadIdx.x] = 0u;
}

template<int D>
__global__ void sqnorm_kernel(const float* __restrict__ X, float* __restrict__ n2) {
    int p = blockIdx.x * 256 + threadIdx.x;
    float s = 0.f;
    #pragma unroll
    for (int k = 0; k < D; k += 4) {
        float4 v = *(const float4*)&X[(size_t)p * D + k];
        s += v.x * v.x + v.y * v.y + v.z * v.z + v.w * v.w;
    }
    n2[p] = s;
}

// stage-1: pos [16384][3] -> bf16 hi/lo planes [16384][32] (cols 3..31 zero) + n2
__global__ void packX0_kernel(const float* __restrict__ pos,
                              unsigned short* __restrict__ Xh, unsigned short* __restrict__ Xl,
                              float* __restrict__ n2) {
    int p = blockIdx.x * 256 + threadIdx.x;
    float x = pos[p * 3 + 0], y = pos[p * 3 + 1], z = pos[p * 3 + 2];
    n2[p] = x * x + y * y + z * z;
    ushort4 h = {0, 0, 0, 0}, l = {0, 0, 0, 0};
    split_bf16(x, h.x, l.x); split_bf16(y, h.y, l.y); split_bf16(z, h.z, l.z);
    ushort4 zed = {0, 0, 0, 0};
    *(ushort4*)&Xh[(size_t)p * 32] = h;
    *(ushort4*)&Xl[(size_t)p * 32] = l;
    #pragma unroll
    for (int c = 4; c < 32; c += 4) {
        *(ushort4*)&Xh[(size_t)p * 32 + c] = zed;
        *(ushort4*)&Xl[(size_t)p * 32 + c] = zed;
    }
}

// pack X [16384 x K] fp32 -> bf16 hi/lo planes
__global__ void packX_kernel(const float* __restrict__ X,
                             unsigned short* __restrict__ Xh, unsigned short* __restrict__ Xl) {
    int e = blockIdx.x * 256 + threadIdx.x;
    float4 v = *(const float4*)&X[4 * (size_t)e];
    ushort4 h, l;
    split_bf16(v.x, h.x, l.x); split_bf16(v.y, h.y, l.y);
    split_bf16(v.z, h.z, l.z); split_bf16(v.w, h.w, l.w);
    *(ushort4*)&Xh[4 * (size_t)e] = h;
    *(ushort4*)&Xl[4 * (size_t)e] = l;
}

// W [2d][od] -> W^T hi/lo planes [2od][dpad]: n<od: U = W_top - W_bot; else V = W_bot
__global__ void packWt_kernel(const float* __restrict__ W,
                              unsigned short* __restrict__ Bh, unsigned short* __restrict__ Bl,
                              int d, int dpad, int od) {
    int e = blockIdx.x * 256 + threadIdx.x;
    int n = e / dpad, k = e - n * dpad;
    float v = 0.f;
    if (k < d) v = (n < od) ? (W[k * od + n] - W[(d + k) * od + n])
                            : W[(d + k) * od + (n - od)];
    unsigned short h, l;
    split_bf16(v, h, l);
    Bh[e] = h; Bl[e] = l;
}

// pack A = concat(x1,x2,x3) [16384 x 448] into bf16 hi/lo planes
__global__ void packA_kernel(const float* __restrict__ x1, const float* __restrict__ x2,
                             const float* __restrict__ x3,
                             unsigned short* __restrict__ Ah, unsigned short* __restrict__ Al) {
    int e = blockIdx.x * 256 + threadIdx.x;
    int m = e / 112, c4 = (e - m * 112) * 4;
    float4 v;
    if (c4 < 64)       v = *(const float4*)&x1[(size_t)m * 64 + c4];
    else if (c4 < 192) v = *(const float4*)&x2[(size_t)m * 128 + (c4 - 64)];
    else               v = *(const float4*)&x3[(size_t)m * 256 + (c4 - 192)];
    ushort4 h, l;
    split_bf16(v.x, h.x, l.x); split_bf16(v.y, h.y, l.y);
    split_bf16(v.z, h.z, l.z); split_bf16(v.w, h.w, l.w);
    *(ushort4*)&Ah[(size_t)m * 448 + c4] = h;
    *(ushort4*)&Al[(size_t)m * 448 + c4] = l;
}

// pack Wf1^T [1024 x 448] into bf16 hi/lo planes
__global__ void packB_kernel(const float* __restrict__ Wf1,
                             unsigned short* __restrict__ Bh, unsigned short* __restrict__ Bl) {
    int e = blockIdx.x * 256 + threadIdx.x;
    int n = e / 112, k4 = (e - n * 112) * 4;
    ushort4 h, l;
    float v0 = Wf1[(size_t)(k4 + 0) * 1024 + n];
    float v1 = Wf1[(size_t)(k4 + 1) * 1024 + n];
    float v2 = Wf1[(size_t)(k4 + 2) * 1024 + n];
    float v3 = Wf1[(size_t)(k4 + 3) * 1024 + n];
    split_bf16(v0, h.x, l.x); split_bf16(v1, h.y, l.y);
    split_bf16(v2, h.z, l.z); split_bf16(v3, h.w, l.w);
    *(ushort4*)&Bh[(size_t)n * 448 + k4] = h;
    *(ushort4*)&Bl[(size_t)n * 448 + k4] = l;
}

// ---------------- fused kNN v5: deferred exact survivor lists ----------------
// R8 geometry (32 rows, grid 512). Main loop has NO top-k maintenance: pass A keeps
// lane top-3 (feeds exact row threshold tau >= row-24th); pass B appends exact
// (float,q) survivors to a per-row LDS list (atomicAdd, ~5-op body). Exact top-20
// extracted ONCE from ~130 survivors/row after the stream. Overflow (>CAP, rare)
// falls back to direct register insert -- still exact. Ds overlays sB (disjoint
// lifetimes; existing barriers cover the overlay).
#define CAP 200
template<int K>
__global__ __launch_bounds__(256)
void knn_fused_v5(const unsigned short* __restrict__ Xh, const unsigned short* __restrict__ Xl,
                  const float* __restrict__ n2, int* __restrict__ idxout) {
    __shared__ __align__(16) unsigned char smem[64128];
    unsigned short (*sA)[1280] = (unsigned short (*)[1280])smem;            // [2][32*40]  5120 B
    unsigned short (*sB)[5120] = (unsigned short (*)[5120])(smem + 5120);   // [2][128*40] 20480 B
    float* Ds = (float*)(smem + 5120);                                      // 32x132 (overlay on sB)
    float* listD = (float*)(smem + 25600);                                  // 32*200 f32  25600 B
    unsigned short* listI = (unsigned short*)(smem + 51200);                // 32*200 u16  12800 B
    int* cnt = (int*)(smem + 64000);                                        // 32 i32

    const int t = threadIdx.x;
    const int rb = blockIdx.x * 32;
    const int qbase = (rb >> 11) << 11;             // batch-local candidates
    const int w = t >> 6, l = t & 63;
    const int lm = l & 15, lq = l >> 4;
    const int r = t >> 3, sub = t & 7;              // select mapping: 8 threads/row

    if (t < 32) cnt[t] = 0;
    float bd[KNN]; int bi[KNN];
    #pragma unroll
    for (int s = 0; s < KNN; ++s) { bd[s] = 3.0e38f; bi[s] = 0; }
    float worst = 3.0e38f; int wslot = 0;
    float k1 = 3.2e38f, k2 = 3.2e38f, k3 = 3.2e38f; // lane top-3 (k1<=k2<=k3)

    for (int qt = 0; qt < 16; ++qt) {
        const int qb = qbase + qt * 128;
        f32x4 acc[2][2];
        #pragma unroll
        for (int i = 0; i < 2; ++i)
            #pragma unroll
            for (int j = 0; j < 2; ++j) acc[i][j] = (f32x4){0.f, 0.f, 0.f, 0.f};

        for (int kc = 0; kc < K; kc += 32) {
            __syncthreads();                        // prev select done reading Ds (=sB)
            #pragma unroll
            for (int i = 0; i < 5; ++i) {           // 1280 16B chunks: A 256, B 1024
                int c = t + i * 256;
                const unsigned short* gsrc;
                unsigned short* ldst;
                if (c < 256) {
                    int idx = c & 127, m = idx >> 2, q = idx & 3;
                    int plane = (c >> 7) & 1;
                    gsrc = (plane ? Xl : Xh) + (size_t)(rb + m) * K + kc + q * 8;
                    ldst = &sA[plane][m * 40 + q * 8];
                } else {
                    int c2 = c - 256;
                    int idx = c2 & 511, m = idx >> 2, q = idx & 3;
                    int plane = c2 >> 9;
                    gsrc = (plane ? Xl : Xh) + (size_t)(qb + m) * K + kc + q * 8;
                    ldst = &sB[plane][m * 40 + q * 8];
                }
                *(uint4*)ldst = *(const uint4*)gsrc;
            }
            __syncthreads();
            b16x8 ah[2], al[2], bh[2], bl[2];
            #pragma unroll
            for (int rt = 0; rt < 2; ++rt) {
                int off = (rt * 16 + lm) * 40 + lq * 8;
                ah[rt] = *(const b16x8*)&sA[0][off];
                al[rt] = *(const b16x8*)&sA[1][off];
            }
            #pragma unroll
            for (int ct = 0; ct < 2; ++ct) {
                int off = (w * 32 + ct * 16 + lm) * 40 + lq * 8;
                bh[ct] = *(const b16x8*)&sB[0][off];
                bl[ct] = *(const b16x8*)&sB[1][off];
            }
            #pragma unroll
            for (int rt = 0; rt < 2; ++rt)
                #pragma unroll
                for (int ct = 0; ct < 2; ++ct) {
                    acc[rt][ct] = __builtin_amdgcn_mfma_f32_16x16x32_bf16(ah[rt], bh[ct], acc[rt][ct], 0, 0, 0);
                    acc[rt][ct] = __builtin_amdgcn_mfma_f32_16x16x32_bf16(ah[rt], bl[ct], acc[rt][ct], 0, 0, 0);
                    acc[rt][ct] = __builtin_amdgcn_mfma_f32_16x16x32_bf16(al[rt], bh[ct], acc[rt][ct], 0, 0, 0);
                }
        }
        float nv[2];
        #pragma unroll
        for (int ct = 0; ct < 2; ++ct) nv[ct] = n2[qb + w * 32 + ct * 16 + lm];
        __syncthreads();                            // all waves' sB frag reads done
        #pragma unroll
        for (int rt = 0; rt < 2; ++rt)
            #pragma unroll
            for (int ct = 0; ct < 2; ++ct)
                #pragma unroll
                for (int rr = 0; rr < 4; ++rr)
                    Ds[(rt * 16 + lq * 4 + rr) * 132 + w * 32 + ct * 16 + lm] =
                        nv[ct] - 2.f * acc[rt][ct][rr];
        __syncthreads();
        // pass A: load 16 values, update lane top-3 (cheap)
        float vv[16];
        #pragma unroll
        for (int g = 0; g < 4; ++g) {
            float4 v = *(const float4*)&Ds[r * 132 + 16 * sub + 4 * g];
            vv[4 * g + 0] = v.x; vv[4 * g + 1] = v.y;
            vv[4 * g + 2] = v.z; vv[4 * g + 3] = v.w;
        }
        #pragma unroll
        for (int j = 0; j < 16; ++j) {
            float v = vv[j];
            if (v < k3) {
                if (v < k1)      { k3 = k2; k2 = k1; k1 = v; }
                else if (v < k2) { k3 = k2; k2 = v; }
                else               k3 = v;
            }
        }
        // tau = max over the row's 8 lanes of lane-3rd-best (>= row 24th-smallest)
        float tau = k3;
        #pragma unroll
        for (int m = 1; m < 8; m <<= 1) tau = fmaxf(tau, __shfl_xor(tau, m, 64));
        // pass B: append exact survivors (tiny body; no top-k work in main loop)
        const int q0 = qt * 128 + 16 * sub;
        #pragma unroll
        for (int j = 0; j < 16; ++j) {
            float v = vv[j];
            if (v <= tau) {
                int pos = atomicAdd(&cnt[r], 1);
                if (pos < CAP) {
                    listD[r * CAP + pos] = v;
                    listI[r * CAP + pos] = (unsigned short)(q0 + j);
                } else if (v < worst) {
                    topk_insert(bd, bi, worst, wslot, v, q0 + j);   // overflow fallback (rare, exact)
                }
            }
        }
    }

    // ---- one-time exact extraction from the survivor list ----
    __syncthreads();                                // all waves done (Ds/sB quiet)
    const int nfull = cnt[r] < CAP ? cnt[r] : CAP;
    for (int i = sub; i < nfull; i += 8) {
        float v = listD[r * CAP + i];
        if (v < worst) topk_insert(bd, bi, worst, wslot, v, (int)listI[r * CAP + i]);
    }
    // merge 8 register lists of 20 -> top-20 per row (R8-verified pattern)
    int* DsI = (int*)Ds;                            // row stride 132 ints (row-private now)
    float mv = 3.3e38f; int mq = 1 << 20, mj = 0;
    #pragma unroll
    for (int s = 0; s < KNN; ++s) {
        float x = bd[s]; int q = bi[s];
        if (x < mv || (x == mv && q < mq)) { mv = x; mq = q; mj = s; }
    }
    for (int round = 0; round < KNN; ++round) {
        float rv = mv; int rq = mq;
        #pragma unroll
        for (int m = 1; m < 8; m <<= 1) {
            float ov = __shfl_xor(rv, m, 64);
            int   oq = __shfl_xor(rq, m, 64);
            if (ov < rv || (ov == rv && oq < rq)) { rv = ov; rq = oq; }
        }
        if (sub == 0) DsI[r * 132 + round] = rq;
        if (mv == rv && mq == rq) {                 // I own the winner: consume + rescan
            #pragma unroll
            for (int s = 0; s < KNN; ++s) if (s == mj) bd[s] = 3.3e38f;
            mv = 3.3e38f; mq = 1 << 20; mj = 0;
            #pragma unroll
            for (int s = 0; s < KNN; ++s) {
                float x = bd[s]; int q = bi[s];
                if (x < mv || (x == mv && q < mq)) { mv = x; mq = q; mj = s; }
            }
        }
    }
    // same-wave visibility within each 8-lane row group: no barrier needed
    for (int s = sub; s < KNN; s += 8)
        idxout[(size_t)(rb + r) * KNN + s] = qbase + DsI[r * 132 + s];
}

// ---------------- UV projection: split-bf16 MFMA (all stages) ----------------
template<int K>
__global__ __launch_bounds__(256)
void gemm_uv_mfma(const unsigned short* __restrict__ Ah, const unsigned short* __restrict__ Al,
                  const unsigned short* __restrict__ Bh, const unsigned short* __restrict__ Bl,
                  float* __restrict__ C, int N) {
    __shared__ __align__(16) unsigned char smem[40960];
    unsigned short (*sA)[5120] = (unsigned short (*)[5120])smem;
    unsigned short (*sB)[5120] = (unsigned short (*)[5120])(smem + 20480);
    float* tile = (float*)smem;

    const int t = threadIdx.x;
    const int rb = blockIdx.x * 128, nb = blockIdx.y * 128;
    const int w = t >> 6, l = t & 63;
    const int wm = w & 1, wn = w >> 1;
    const int lm = l & 15, lq = l >> 4;

    f32x4 acc[4][4];
    #pragma unroll
    for (int i = 0; i < 4; ++i)
        #pragma unroll
        for (int j = 0; j < 4; ++j) acc[i][j] = (f32x4){0.f, 0.f, 0.f, 0.f};

    for (int kc = 0; kc < K; kc += 32) {
        __syncthreads();
        #pragma unroll
        for (int i = 0; i < 8; ++i) {
            int c = t + i * 256;
            int idx = c & 511, m = idx >> 2, q = idx & 3;
            int plane = (c >> 9) & 1;
            const unsigned short* gsrc;
            unsigned short* ldst;
            if (c < 1024) {
                gsrc = (plane ? Al : Ah) + (size_t)(rb + m) * K + kc + q * 8;
                ldst = &sA[plane][m * 40 + q * 8];
            } else {
                gsrc = (plane ? Bl : Bh) + (size_t)(nb + m) * K + kc + q * 8;
                ldst = &sB[plane][m * 40 + q * 8];
            }
            *(uint4*)ldst = *(const uint4*)gsrc;
        }
        __syncthreads();
        b16x8 ah[4], al[4], bh[4], bl[4];
        #pragma unroll
        for (int mt = 0; mt < 4; ++mt) {
            int off = (wm * 64 + mt * 16 + lm) * 40 + lq * 8;
            ah[mt] = *(const b16x8*)&sA[0][off];
            al[mt] = *(const b16x8*)&sA[1][off];
        }
        #pragma unroll
        for (int nt = 0; nt < 4; ++nt) {
            int off = (wn * 64 + nt * 16 + lm) * 40 + lq * 8;
            bh[nt] = *(const b16x8*)&sB[0][off];
            bl[nt] = *(const b16x8*)&sB[1][off];
        }
        #pragma unroll
        for (int mt = 0; mt < 4; ++mt)
            #pragma unroll
            for (int nt = 0; nt < 4; ++nt) {
                acc[mt][nt] = __builtin_amdgcn_mfma_f32_16x16x32_bf16(ah[mt], bh[nt], acc[mt][nt], 0, 0, 0);
                acc[mt][nt] = __builtin_amdgcn_mfma_f32_16x16x32_bf16(ah[mt], bl[nt], acc[mt][nt], 0, 0, 0);
                acc[mt][nt] = __builtin_amdgcn_mfma_f32_16x16x32_bf16(al[mt], bh[nt], acc[mt][nt], 0, 0, 0);
            }
    }
    #pragma unroll
    for (int ch = 0; ch < 4; ++ch) {
        __syncthreads();
        if (wm == (ch >> 1)) {
            const int mt0 = (ch & 1) * 2;
            #pragma unroll
            for (int mm = 0; mm < 2; ++mm) {
                #pragma unroll
                for (int nt = 0; nt < 4; ++nt)
                    #pragma unroll
                    for (int rr = 0; rr < 4; ++rr)
                        tile[(mm * 16 + lq * 4 + rr) * 132 + wn * 64 + nt * 16 + lm] =
                            acc[mt0 + mm][nt][rr];
            }
        }
        __syncthreads();
        const int rowbase = rb + ch * 32;
        #pragma unroll
        for (int i = 0; i < 4; ++i) {
            int e = t + i * 256;
            int lr = e >> 5, c4 = (e & 31) * 4;
            *(float4*)&C[(size_t)(rowbase + lr) * N + nb + c4] = *(const float4*)&tile[lr * 132 + c4];
        }
    }
}

// ---------------- fc1: split-bf16 MFMA GEMM + fused max-pool ----------------
__global__ __launch_bounds__(256)
void gemm_fc1_mfma(const unsigned short* __restrict__ Ah, const unsigned short* __restrict__ Al,
                   const unsigned short* __restrict__ Bh, const unsigned short* __restrict__ Bl,
                   const float* __restrict__ bias, unsigned* __restrict__ pool) {
    __shared__ unsigned short sA[2][128 * 40];
    __shared__ unsigned short sB[2][128 * 40];
    const int t = threadIdx.x;
    const int nb = blockIdx.y * 128, mb = blockIdx.x * 128;
    const int w = t >> 6, l = t & 63;
    const int wm = w & 1, wn = w >> 1;
    const int lm = l & 15, lq = l >> 4;

    f32x4 acc[4][4];
    #pragma unroll
    for (int i = 0; i < 4; ++i)
        #pragma unroll
        for (int j = 0; j < 4; ++j) acc[i][j] = (f32x4){0.f, 0.f, 0.f, 0.f};

    for (int kc = 0; kc < 448; kc += 32) {
        __syncthreads();
        #pragma unroll
        for (int i = 0; i < 8; ++i) {
            int c = t + i * 256;
            int idx = c & 511, m = idx >> 2, q = idx & 3;
            int plane = (c >> 9) & 1;
            const unsigned short* gsrc;
            unsigned short* ldst;
            if (c < 1024) {
                gsrc = (plane ? Al : Ah) + (size_t)(mb + m) * 448 + kc + q * 8;
                ldst = &sA[plane][m * 40 + q * 8];
            } else {
                gsrc = (plane ? Bl : Bh) + (size_t)(nb + m) * 448 + kc + q * 8;
                ldst = &sB[plane][m * 40 + q * 8];
            }
            *(uint4*)ldst = *(const uint4*)gsrc;
        }
        __syncthreads();
        b16x8 ah[4], al[4], bh[4], bl[4];
        #pragma unroll
        for (int mt = 0; mt < 4; ++mt) {
            int off = (wm * 64 + mt * 16 + lm) * 40 + lq * 8;
            ah[mt] = *(const b16x8*)&sA[0][off];
            al[mt] = *(const b16x8*)&sA[1][off];
        }
        #pragma unroll
        for (int nt = 0; nt < 4; ++nt) {
            int off = (wn * 64 + nt * 16 + lm) * 40 + lq * 8;
            bh[nt] = *(const b16x8*)&sB[0][off];
            bl[nt] = *(const b16x8*)&sB[1][off];
        }
        #pragma unroll
        for (int mt = 0; mt < 4; ++mt)
            #pragma unroll
            for (int nt = 0; nt < 4; ++nt) {
                acc[mt][nt] = __builtin_amdgcn_mfma_f32_16x16x32_bf16(ah[mt], bh[nt], acc[mt][nt], 0, 0, 0);
                acc[mt][nt] = __builtin_amdgcn_mfma_f32_16x16x32_bf16(ah[mt], bl[nt], acc[mt][nt], 0, 0, 0);
                acc[mt][nt] = __builtin_amdgcn_mfma_f32_16x16x32_bf16(al[mt], bh[nt], acc[mt][nt], 0, 0, 0);
            }
    }
    const int batch = blockIdx.x >> 4;
    #pragma unroll
    for (int nt = 0; nt < 4; ++nt) {
        float m0 = -3.4e38f;
        #pragma unroll
        for (int mt = 0; mt < 4; ++mt)
            #pragma unroll
            for (int rr = 0; rr < 4; ++rr) m0 = fmaxf(m0, acc[mt][nt][rr]);
        m0 = fmaxf(m0, __shfl_xor(m0, 16, 64));
        m0 = fmaxf(m0, __shfl_xor(m0, 32, 64));
        if (l < 16) {
            int col = nb + wn * 64 + nt * 16 + l;
            atomicMax(&pool[batch * 1024 + col], f2o(m0 + bias[col]));
        }
    }
}

// ---------------- edge-conv aggregate ----------------
__global__ void agg_kernel(const float* __restrict__ UV, const int* __restrict__ idx,
                           const float* __restrict__ bias, float* __restrict__ xo, int od) {
    const int p = ((blockIdx.x & 7) << 11) + (blockIdx.x >> 3);
    const int c = threadIdx.x;
    const float u = UV[(size_t)p * 2 * od + c];
    float m = -3.4e38f;
    #pragma unroll
    for (int k = 0; k < KNN; ++k) {
        int j = idx[p * KNN + k];
        m = fmaxf(m, UV[(size_t)j * 2 * od + od + c]);
    }
    xo[(size_t)p * od + c] = u + bias[c] + m;
}

// ---------------- head: split-k GEMM + per-column BN ----------------
template<int IND, int OD, int KSEG, bool UNMAP>
__global__ __launch_bounds__(256)
void head_gemm_k(const float* __restrict__ in, const float* __restrict__ W,
                 float* __restrict__ P) {
    const int KL = IND / KSEG;
    __shared__ float xs[8][IND / KSEG];
    const int t = threadIdx.x;
    const int kb = blockIdx.y * KL;
    const int cb = blockIdx.x * 64;
    for (int e = t; e < 8 * KL; e += 256) {
        int r = e / KL, k = e - r * KL;
        if (UNMAP) xs[r][k] = o2f(((const unsigned*)in)[r * IND + kb + k]);
        else       xs[r][k] = in[r * IND + kb + k];
    }
    __syncthreads();
    const int c = t & 63, rr = t >> 6;
    float a0 = 0.f, a1 = 0.f;
    #pragma unroll 4
    for (int k = 0; k < KL; ++k) {
        float wv = W[(size_t)(kb + k) * OD + cb + c];
        a0 += xs[2 * rr][k] * wv;
        a1 += xs[2 * rr + 1][k] * wv;
    }
    P[(size_t)(blockIdx.y * 8 + 2 * rr) * OD + cb + c]     = a0;
    P[(size_t)(blockIdx.y * 8 + 2 * rr + 1) * OD + cb + c] = a1;
}

template<int OD, int KSEG>
__global__ void head_bn2(const float* __restrict__ P, const float* __restrict__ bias,
                         const float* __restrict__ g, const float* __restrict__ be,
                         float* __restrict__ out) {
    const int c = blockIdx.x * 256 + threadIdx.x;
    float a[8];
    #pragma unroll
    for (int r = 0; r < 8; ++r) {
        float s = bias[c];
        #pragma unroll
        for (int ks = 0; ks < KSEG; ++ks) s += P[(size_t)(ks * 8 + r) * OD + c];
        a[r] = s;
    }
    float mu = 0.f;
    #pragma unroll
    for (int r = 0; r < 8; ++r) mu += a[r];
    mu *= 0.125f;
    float vr = 0.f;
    #pragma unroll
    for (int r = 0; r < 8; ++r) { float d = a[r] - mu; vr += d * d; }
    vr *= 0.125f;
    float is = rsqrtf(vr + 1e-5f) * g[c];
    #pragma unroll
    for (int r = 0; r < 8; ++r)
        out[r * OD + c] = fmaxf(is * (a[r] - mu) + be[c], 0.f);
}

// final Lin [8,256]@[256,23] + log_softmax
__global__ void head3_kernel(const float* __restrict__ x, const float* __restrict__ W,
                             const float* __restrict__ b, float* __restrict__ out) {
    __shared__ float xs[8 * 256];
    __shared__ float lg[8][23];
    __shared__ float red[8][2];
    const int t = threadIdx.x;
    for (int e = t; e < 2048; e += 256) xs[e] = x[e];
    __syncthreads();
    if (t < 184) {
        int r = t / 23, c = t - 23 * r;
        float a = b[c];
        for (int k = 0; k < 256; ++k) a += xs[r * 256 + k] * W[k * 23 + c];
        lg[r][c] = a;
    }
    __syncthreads();
    if (t < 8) {
        float mx = -3.4e38f;
        for (int c = 0; c < 23; ++c) mx = fmaxf(mx, lg[t][c]);
        float s = 0.f;
        for (int c = 0; c < 23; ++c) s += expf(lg[t][c] - mx);
        red[t][0] = mx; red[t][1] = logf(s);
    }
    __syncthreads();
    if (t < 184) {
        int r = t / 23, c = t - 23 * r;
        out[t] = lg[r][c] - red[r][0] - red[r][1];
    }
}

// ---------------- launcher ----------------
extern "C" void kernel_launch(void* const* d_in, const int* in_sizes, int n_in,
                              void* d_out, int out_size, void* d_ws, size_t ws_size,
                              hipStream_t stream) {
    (void)in_sizes; (void)n_in; (void)out_size; (void)ws_size;
    const float* pos = (const float*)d_in[0];
    const float* W1  = (const float*)d_in[2];  const float* b1  = (const float*)d_in[3];
    const float* W2  = (const float*)d_in[4];  const float* b2  = (const float*)d_in[5];
    const float* W3  = (const float*)d_in[6];  const float* b3  = (const float*)d_in[7];
    const float* Wf1 = (const float*)d_in[8];  const float* bf1 = (const float*)d_in[9];
    const float* Wa  = (const float*)d_in[10]; const float* ba  = (const float*)d_in[11];
    const float* ga  = (const float*)d_in[12]; const float* bea = (const float*)d_in[13];
    const float* Wb  = (const float*)d_in[14]; const float* bb  = (const float*)d_in[15];
    const float* gb  = (const float*)d_in[16]; const float* beb = (const float*)d_in[17];
    const float* Wc  = (const float*)d_in[18]; const float* bc  = (const float*)d_in[19];

    char* ws = (char*)d_ws;
    float*    n2   = (float*)(ws + OFF_N2);
    int*      idx  = (int*)(ws + OFF_IDX);
    unsigned* pool = (unsigned*)(ws + OFF_POOL);
    float*    C1   = (float*)(ws + OFF_C1);
    float*    C2   = (float*)(ws + OFF_C2);
    float*    x1   = (float*)(ws + OFF_X1);
    float*    x2   = (float*)(ws + OFF_X2);
    float*    x3   = (float*)(ws + OFF_X3);
    float*    UV   = (float*)(ws + OFF_UV);
    float*    P1   = (float*)(ws + OFF_P1);
    float*    P2   = (float*)(ws + OFF_P2);
    unsigned short* Xph  = (unsigned short*)(ws + OFF_XPH);
    unsigned short* Xpl  = (unsigned short*)(ws + OFF_XPL);
    unsigned short* Apkh = (unsigned short*)(ws + OFF_APKH);
    unsigned short* Apkl = (unsigned short*)(ws + OFF_APKL);
    unsigned short* Bth  = (unsigned short*)(ws + OFF_BTH);
    unsigned short* Btl  = (unsigned short*)(ws + OFF_BTL);
    unsigned short* Wt1h = (unsigned short*)(ws + OFF_WT1H);
    unsigned short* Wt1l = (unsigned short*)(ws + OFF_WT1L);
    unsigned short* Wt2h = (unsigned short*)(ws + OFF_WT2H);
    unsigned short* Wt2l = (unsigned short*)(ws + OFF_WT2L);
    unsigned short* Wt3h = (unsigned short*)(ws + OFF_WT3H);
    unsigned short* Wt3l = (unsigned short*)(ws + OFF_WT3L);

    // prep
    init_pool_kernel<<<32, 256, 0, stream>>>(pool);
    packWt_kernel<<<16,  256, 0, stream>>>(W1, Wt1h, Wt1l, 3,   32,  64);
    packWt_kernel<<<64,  256, 0, stream>>>(W2, Wt2h, Wt2l, 64,  64,  128);
    packWt_kernel<<<256, 256, 0, stream>>>(W3, Wt3h, Wt3l, 128, 128, 256);

    // edge conv 1 (d=3 padded to 32)
    packX0_kernel<<<64, 256, 0, stream>>>(pos, Xph, Xpl, n2);
    knn_fused_v5<32><<<512, 256, 0, stream>>>(Xph, Xpl, n2, idx);
    gemm_uv_mfma<32><<<dim3(128, 1), 256, 0, stream>>>(Xph, Xpl, Wt1h, Wt1l, UV, 128);
    agg_kernel<<<NPTS, 64, 0, stream>>>(UV, idx, b1, x1, 64);

    // edge conv 2 (64 -> 128)
    sqnorm_kernel<64><<<64, 256, 0, stream>>>(x1, n2);
    packX_kernel<<<1024, 256, 0, stream>>>(x1, Xph, Xpl);
    knn_fused_v5<64><<<512, 256, 0, stream>>>(Xph, Xpl, n2, idx);
    gemm_uv_mfma<64><<<dim3(128, 2), 256, 0, stream>>>(Xph, Xpl, Wt2h, Wt2l, UV, 256);
    agg_kernel<<<NPTS, 128, 0, stream>>>(UV, idx, b2, x2, 128);

    // edge conv 3 (128 -> 256)
    sqnorm_kernel<128><<<64, 256, 0, stream>>>(x2, n2);
    packX_kernel<<<2048, 256, 0, stream>>>(x2, Xph, Xpl);
    knn_fused_v5<128><<<512, 256, 0, stream>>>(Xph, Xpl, n2, idx);
    gemm_uv_mfma<128><<<dim3(128, 4), 256, 0, stream>>>(Xph, Xpl, Wt3h, Wt3l, UV, 512);
    agg_kernel<<<NPTS, 256, 0, stream>>>(UV, idx, b3, x3, 256);

    // fc1 (MFMA) + fused max pool
    packA_kernel<<<7168, 256, 0, stream>>>(x1, x2, x3, Apkh, Apkl);
    packB_kernel<<<448,  256, 0, stream>>>(Wf1, Bth, Btl);
    gemm_fc1_mfma<<<dim3(128, 8), 256, 0, stream>>>(Apkh, Apkl, Bth, Btl, bf1, pool);

    // head: split-k GEMM + BN
    head_gemm_k<1024, 512, 8, true ><<<dim3(8, 8), 256, 0, stream>>>((const float*)pool, Wa, P1);
    head_bn2<512, 8><<<2, 256, 0, stream>>>(P1, ba, ga, bea, C1);
    head_gemm_k<512, 256, 4, false><<<dim3(4, 4), 256, 0, stream>>>(C1, Wb, P2);
    head_bn2<256, 4><<<1, 256, 0, stream>>>(P2, bb, gb, beb, C2);
    head3_kernel<<<1, 256, 0, stream>>>(C2, Wc, bc, (float*)d_out);
}